// Round 1
// baseline (895.895 us; speedup 1.0000x reference)
//
#include <hip/hip_runtime.h>

// Problem constants
#define B_   16
#define C_   512
#define CI_  256
#define N_   1024        // H*W = 32*32
#define EPS_ 1e-5f

// ---------------------------------------------------------------------------
// Generic 64x64 tile, BK=16, 256 threads (16x16), 4x4 micro-tile per thread.
// LDS layout: As[k][i] (A transposed into LDS), Bs[k][n]. Pad 68 to avoid
// 4-way bank conflicts on transposed stores.
// ---------------------------------------------------------------------------

// K1: embed.  O[i,n] = sum_c W[i,c] * X[c,n] + bias[i]
// blockIdx.z = lb*2 + st  (lb = chunk-local batch, st: 0=rgb 1=flow)
__global__ __launch_bounds__(256) void k_embed(
    const float* __restrict__ rgb, const float* __restrict__ flow,
    const float* __restrict__ wg_rgb, const float* __restrict__ bg_rgb,
    const float* __restrict__ wg_flow, const float* __restrict__ bg_flow,
    float* __restrict__ re, float* __restrict__ fe, int b0)
{
    const int bz = blockIdx.z;
    const int lb = bz >> 1, st = bz & 1;
    const int gb = b0 + lb;
    const float* X = (st ? flow : rgb) + (size_t)gb * C_ * N_;
    const float* W = st ? wg_flow : wg_rgb;
    const float* bias = st ? bg_flow : bg_rgb;
    float* O = (st ? fe : re) + (size_t)lb * CI_ * N_;

    const int i0 = blockIdx.y * 64;   // over CI
    const int n0 = blockIdx.x * 64;   // over N

    __shared__ float As[16][68];
    __shared__ float Bs[16][68];
    const int tid = threadIdx.y * 16 + threadIdx.x;
    float acc[4][4] = {};

    for (int k0 = 0; k0 < C_; k0 += 16) {
#pragma unroll
        for (int r = 0; r < 4; ++r) {
            int idx = tid + r * 256;
            int ai = idx >> 4, ak = idx & 15;
            As[ak][ai] = W[(size_t)(i0 + ai) * C_ + k0 + ak];
        }
#pragma unroll
        for (int r = 0; r < 4; ++r) {
            int idx = tid + r * 256;
            int bk = idx >> 6, bn = idx & 63;
            Bs[bk][bn] = X[(size_t)(k0 + bk) * N_ + n0 + bn];
        }
        __syncthreads();
#pragma unroll
        for (int k = 0; k < 16; ++k) {
            float a[4], bb[4];
#pragma unroll
            for (int q = 0; q < 4; ++q) a[q] = As[k][threadIdx.y * 4 + q];
#pragma unroll
            for (int q = 0; q < 4; ++q) bb[q] = Bs[k][threadIdx.x * 4 + q];
#pragma unroll
            for (int qi = 0; qi < 4; ++qi)
#pragma unroll
                for (int qj = 0; qj < 4; ++qj)
                    acc[qi][qj] = fmaf(a[qi], bb[qj], acc[qi][qj]);
        }
        __syncthreads();
    }
#pragma unroll
    for (int qi = 0; qi < 4; ++qi) {
        int i = i0 + threadIdx.y * 4 + qi;
        float bv = bias[i];
#pragma unroll
        for (int qj = 0; qj < 4; ++qj)
            O[(size_t)i * N_ + n0 + threadIdx.x * 4 + qj] = acc[qi][qj] + bv;
    }
}

// K2: scores. S[n,m] = sum_i re[i,n] * fe[i,m]
__global__ __launch_bounds__(256) void k_scores(
    const float* __restrict__ re, const float* __restrict__ fe,
    float* __restrict__ S)
{
    const int lb = blockIdx.z;
    const float* A = re + (size_t)lb * CI_ * N_;
    const float* Bf = fe + (size_t)lb * CI_ * N_;
    float* So = S + (size_t)lb * N_ * N_;
    const int n0 = blockIdx.y * 64;
    const int m0 = blockIdx.x * 64;

    __shared__ float As[16][68];
    __shared__ float Bs[16][68];
    const int tid = threadIdx.y * 16 + threadIdx.x;
    float acc[4][4] = {};

    for (int k0 = 0; k0 < CI_; k0 += 16) {
#pragma unroll
        for (int r = 0; r < 4; ++r) {
            int idx = tid + r * 256;
            int kk = idx >> 6, nn = idx & 63;
            As[kk][nn] = A[(size_t)(k0 + kk) * N_ + n0 + nn];
            Bs[kk][nn] = Bf[(size_t)(k0 + kk) * N_ + m0 + nn];
        }
        __syncthreads();
#pragma unroll
        for (int k = 0; k < 16; ++k) {
            float a[4], bb[4];
#pragma unroll
            for (int q = 0; q < 4; ++q) a[q] = As[k][threadIdx.y * 4 + q];
#pragma unroll
            for (int q = 0; q < 4; ++q) bb[q] = Bs[k][threadIdx.x * 4 + q];
#pragma unroll
            for (int qi = 0; qi < 4; ++qi)
#pragma unroll
                for (int qj = 0; qj < 4; ++qj)
                    acc[qi][qj] = fmaf(a[qi], bb[qj], acc[qi][qj]);
        }
        __syncthreads();
    }
#pragma unroll
    for (int qi = 0; qi < 4; ++qi)
#pragma unroll
        for (int qj = 0; qj < 4; ++qj)
            So[(size_t)(n0 + threadIdx.y * 4 + qi) * N_ + m0 + threadIdx.x * 4 + qj] = acc[qi][qj];
}

// K3: row softmax stats (over m, last dim). One block per (lb,n) row.
__global__ __launch_bounds__(256) void k_rowstats(
    const float* __restrict__ S, float* __restrict__ rmax, float* __restrict__ rinv)
{
    const int row = blockIdx.x;                // lb*N_ + n
    const float* Sr = S + (size_t)row * N_;
    const int t = threadIdx.x;
    float v[4];
    float mx = -1e30f;
#pragma unroll
    for (int r = 0; r < 4; ++r) { v[r] = Sr[t + r * 256]; mx = fmaxf(mx, v[r]); }
#pragma unroll
    for (int off = 32; off > 0; off >>= 1) mx = fmaxf(mx, __shfl_down(mx, off));
    __shared__ float red[8];
    if ((t & 63) == 0) red[t >> 6] = mx;
    __syncthreads();
    mx = fmaxf(fmaxf(red[0], red[1]), fmaxf(red[2], red[3]));
    float s = 0.f;
#pragma unroll
    for (int r = 0; r < 4; ++r) s += __expf(v[r] - mx);
#pragma unroll
    for (int off = 32; off > 0; off >>= 1) s += __shfl_down(s, off);
    if ((t & 63) == 0) red[4 + (t >> 6)] = s;
    __syncthreads();
    if (t == 0) {
        float tot = red[4] + red[5] + red[6] + red[7];
        rmax[row] = mx;
        rinv[row] = 1.0f / tot;
    }
}

// K4: column softmax stats (over n). Thread t owns column m = bx*256+t, online.
__global__ __launch_bounds__(256) void k_colstats(
    const float* __restrict__ S, float* __restrict__ cmax, float* __restrict__ cinv)
{
    const int lb = blockIdx.y;
    const int m = blockIdx.x * 256 + threadIdx.x;
    const float* Sb = S + (size_t)lb * N_ * N_;
    float mx = -1e30f, sum = 0.f;
    for (int n = 0; n < N_; ++n) {
        float v = Sb[(size_t)n * N_ + m];
        float nmx = fmaxf(mx, v);
        sum = sum * __expf(mx - nmx) + __expf(v - nmx);
        mx = nmx;
    }
    cmax[lb * N_ + m] = mx;
    cinv[lb * N_ + m] = 1.0f / sum;
}

// K5: rgb_y[i,n] = sum_m fe[i,m] * P[n,m],  P[n,m]=exp(S[n,m]-rmax[n])*rinv[n]
__global__ __launch_bounds__(256) void k_rgby(
    const float* __restrict__ fe, const float* __restrict__ S,
    const float* __restrict__ rmax, const float* __restrict__ rinv,
    float* __restrict__ ry)
{
    const int lb = blockIdx.z;
    const float* A = fe + (size_t)lb * CI_ * N_;
    const float* Sb = S + (size_t)lb * N_ * N_;
    float* O = ry + (size_t)lb * CI_ * N_;
    const int i0 = blockIdx.y * 64;
    const int n0 = blockIdx.x * 64;

    __shared__ float As[16][68];   // As[k=m][i]
    __shared__ float Bs[16][68];   // Bs[k=m][n]
    __shared__ float s_rm[64], s_ri[64];
    const int tid = threadIdx.y * 16 + threadIdx.x;
    if (tid < 64) s_rm[tid] = rmax[lb * N_ + n0 + tid];
    else if (tid < 128) s_ri[tid - 64] = rinv[lb * N_ + n0 + tid - 64];
    __syncthreads();

    float acc[4][4] = {};
    for (int k0 = 0; k0 < N_; k0 += 16) {
#pragma unroll
        for (int r = 0; r < 4; ++r) {
            int idx = tid + r * 256;
            int ai = idx >> 4, ak = idx & 15;
            As[ak][ai] = A[(size_t)(i0 + ai) * N_ + k0 + ak];
        }
#pragma unroll
        for (int r = 0; r < 4; ++r) {
            int idx = tid + r * 256;
            int bn = idx >> 4, bm = idx & 15;
            float s = Sb[(size_t)(n0 + bn) * N_ + k0 + bm];
            Bs[bm][bn] = __expf(s - s_rm[bn]) * s_ri[bn];
        }
        __syncthreads();
#pragma unroll
        for (int k = 0; k < 16; ++k) {
            float a[4], bb[4];
#pragma unroll
            for (int q = 0; q < 4; ++q) a[q] = As[k][threadIdx.y * 4 + q];
#pragma unroll
            for (int q = 0; q < 4; ++q) bb[q] = Bs[k][threadIdx.x * 4 + q];
#pragma unroll
            for (int qi = 0; qi < 4; ++qi)
#pragma unroll
                for (int qj = 0; qj < 4; ++qj)
                    acc[qi][qj] = fmaf(a[qi], bb[qj], acc[qi][qj]);
        }
        __syncthreads();
    }
#pragma unroll
    for (int qi = 0; qi < 4; ++qi)
#pragma unroll
        for (int qj = 0; qj < 4; ++qj)
            O[(size_t)(i0 + threadIdx.y * 4 + qi) * N_ + n0 + threadIdx.x * 4 + qj] = acc[qi][qj];
}

// K6: flow_y[i,m] = sum_n re[i,n] * Q[n,m], Q[n,m]=exp(S[n,m]-cmax[m])*cinv[m]
__global__ __launch_bounds__(256) void k_flowy(
    const float* __restrict__ re, const float* __restrict__ S,
    const float* __restrict__ cmax, const float* __restrict__ cinv,
    float* __restrict__ fy)
{
    const int lb = blockIdx.z;
    const float* A = re + (size_t)lb * CI_ * N_;
    const float* Sb = S + (size_t)lb * N_ * N_;
    float* O = fy + (size_t)lb * CI_ * N_;
    const int i0 = blockIdx.y * 64;
    const int m0 = blockIdx.x * 64;

    __shared__ float As[16][68];   // As[k=n][i]
    __shared__ float Bs[16][68];   // Bs[k=n][m]
    __shared__ float s_cm[64], s_ci[64];
    const int tid = threadIdx.y * 16 + threadIdx.x;
    if (tid < 64) s_cm[tid] = cmax[lb * N_ + m0 + tid];
    else if (tid < 128) s_ci[tid - 64] = cinv[lb * N_ + m0 + tid - 64];
    __syncthreads();

    float acc[4][4] = {};
    for (int k0 = 0; k0 < N_; k0 += 16) {
#pragma unroll
        for (int r = 0; r < 4; ++r) {
            int idx = tid + r * 256;
            int ai = idx >> 4, ak = idx & 15;
            As[ak][ai] = A[(size_t)(i0 + ai) * N_ + k0 + ak];
        }
#pragma unroll
        for (int r = 0; r < 4; ++r) {
            int idx = tid + r * 256;
            int kn = idx >> 6, mm = idx & 63;
            float s = Sb[(size_t)(k0 + kn) * N_ + m0 + mm];
            Bs[kn][mm] = __expf(s - s_cm[mm]) * s_ci[mm];
        }
        __syncthreads();
#pragma unroll
        for (int k = 0; k < 16; ++k) {
            float a[4], bb[4];
#pragma unroll
            for (int q = 0; q < 4; ++q) a[q] = As[k][threadIdx.y * 4 + q];
#pragma unroll
            for (int q = 0; q < 4; ++q) bb[q] = Bs[k][threadIdx.x * 4 + q];
#pragma unroll
            for (int qi = 0; qi < 4; ++qi)
#pragma unroll
                for (int qj = 0; qj < 4; ++qj)
                    acc[qi][qj] = fmaf(a[qi], bb[qj], acc[qi][qj]);
        }
        __syncthreads();
    }
#pragma unroll
    for (int qi = 0; qi < 4; ++qi)
#pragma unroll
        for (int qj = 0; qj < 4; ++qj)
            O[(size_t)(i0 + threadIdx.y * 4 + qi) * N_ + m0 + threadIdx.x * 4 + qj] = acc[qi][qj];
}

// K7: conv2. z[c,n] = sum_i WW[c,i]*Y[i,n] + bw[c]  -> staged into d_out
__global__ __launch_bounds__(256) void k_conv2(
    const float* __restrict__ ry, const float* __restrict__ fy,
    const float* __restrict__ ww_rgb, const float* __restrict__ bw_rgb,
    const float* __restrict__ ww_flow, const float* __restrict__ bw_flow,
    float* __restrict__ out, int b0)
{
    const int bz = blockIdx.z;
    const int lb = bz >> 1, st = bz & 1;
    const int gb = b0 + lb;
    const float* Y = (st ? fy : ry) + (size_t)lb * CI_ * N_;
    const float* W = st ? ww_flow : ww_rgb;
    const float* bias = st ? bw_flow : bw_rgb;
    float* O = out + ((size_t)st * B_ + gb) * C_ * N_;

    const int c0 = blockIdx.y * 64;   // over C=512 -> gridDim.y=8
    const int n0 = blockIdx.x * 64;

    __shared__ float As[16][68];
    __shared__ float Bs[16][68];
    const int tid = threadIdx.y * 16 + threadIdx.x;
    float acc[4][4] = {};

    for (int k0 = 0; k0 < CI_; k0 += 16) {
#pragma unroll
        for (int r = 0; r < 4; ++r) {
            int idx = tid + r * 256;
            int ai = idx >> 4, ak = idx & 15;
            As[ak][ai] = W[(size_t)(c0 + ai) * CI_ + k0 + ak];
        }
#pragma unroll
        for (int r = 0; r < 4; ++r) {
            int idx = tid + r * 256;
            int kk = idx >> 6, nn = idx & 63;
            Bs[kk][nn] = Y[(size_t)(k0 + kk) * N_ + n0 + nn];
        }
        __syncthreads();
#pragma unroll
        for (int k = 0; k < 16; ++k) {
            float a[4], bb[4];
#pragma unroll
            for (int q = 0; q < 4; ++q) a[q] = As[k][threadIdx.y * 4 + q];
#pragma unroll
            for (int q = 0; q < 4; ++q) bb[q] = Bs[k][threadIdx.x * 4 + q];
#pragma unroll
            for (int qi = 0; qi < 4; ++qi)
#pragma unroll
                for (int qj = 0; qj < 4; ++qj)
                    acc[qi][qj] = fmaf(a[qi], bb[qj], acc[qi][qj]);
        }
        __syncthreads();
    }
#pragma unroll
    for (int qi = 0; qi < 4; ++qi) {
        int c = c0 + threadIdx.y * 4 + qi;
        float bv = bias[c];
#pragma unroll
        for (int qj = 0; qj < 4; ++qj)
            O[(size_t)c * N_ + n0 + threadIdx.x * 4 + qj] = acc[qi][qj] + bv;
    }
}

// K8: BN stats per (stream, channel): mean/var over (b,n). 1024 blocks.
__global__ __launch_bounds__(256) void k_bnstats(
    const float* __restrict__ zall,
    const float* __restrict__ gamma_rgb, const float* __restrict__ beta_rgb,
    const float* __restrict__ gamma_flow, const float* __restrict__ beta_flow,
    float* __restrict__ scale, float* __restrict__ shift)
{
    const int st = blockIdx.x >> 9;
    const int c = blockIdx.x & 511;
    const float* z0 = zall + (size_t)st * B_ * C_ * N_ + (size_t)c * N_;
    const int t = threadIdx.x;
    float s = 0.f, ss = 0.f;
    for (int b = 0; b < B_; ++b) {
        const float* zb = z0 + (size_t)b * C_ * N_;
        for (int n = t; n < N_; n += 256) {
            float v = zb[n];
            s += v; ss += v * v;
        }
    }
#pragma unroll
    for (int off = 32; off > 0; off >>= 1) {
        s += __shfl_down(s, off);
        ss += __shfl_down(ss, off);
    }
    __shared__ float rs[4], rss[4];
    if ((t & 63) == 0) { rs[t >> 6] = s; rss[t >> 6] = ss; }
    __syncthreads();
    if (t == 0) {
        float S1 = rs[0] + rs[1] + rs[2] + rs[3];
        float S2 = rss[0] + rss[1] + rss[2] + rss[3];
        const float inv_cnt = 1.0f / (float)(B_ * N_);
        float mean = S1 * inv_cnt;
        float var = S2 * inv_cnt - mean * mean;
        float g = st ? gamma_flow[c] : gamma_rgb[c];
        float be = st ? beta_flow[c] : beta_rgb[c];
        float sc = g * rsqrtf(var + EPS_);
        scale[st * C_ + c] = sc;
        shift[st * C_ + c] = be - mean * sc;
    }
}

// K9: apply BN + residual, in-place on d_out. float4 per thread.
__global__ __launch_bounds__(256) void k_bnapply(
    float* __restrict__ out, const float* __restrict__ rgb,
    const float* __restrict__ flow, const float* __restrict__ scale,
    const float* __restrict__ shift)
{
    const size_t idx = (size_t)blockIdx.x * 256 + threadIdx.x;
    const size_t e = idx * 4;
    const size_t half = (size_t)B_ * C_ * N_;
    const int st = e >= half;
    const size_t rem = e - (size_t)st * half;
    const int c = (int)((rem >> 10) & (C_ - 1));
    const float* x = (st ? flow : rgb) + rem;
    const float sc = scale[st * C_ + c];
    const float sh = shift[st * C_ + c];
    float4 z = *reinterpret_cast<const float4*>(out + e);
    float4 xv = *reinterpret_cast<const float4*>(x);
    float4 rr;
    rr.x = z.x * sc + sh + xv.x;
    rr.y = z.y * sc + sh + xv.y;
    rr.z = z.z * sc + sh + xv.z;
    rr.w = z.w * sc + sh + xv.w;
    *reinterpret_cast<float4*>(out + e) = rr;
}

extern "C" void kernel_launch(void* const* d_in, const int* in_sizes, int n_in,
                              void* d_out, int out_size, void* d_ws, size_t ws_size,
                              hipStream_t stream)
{
    const float* rgb       = (const float*)d_in[0];
    const float* flow      = (const float*)d_in[1];
    const float* wg_rgb    = (const float*)d_in[2];
    const float* bg_rgb    = (const float*)d_in[3];
    const float* wg_flow   = (const float*)d_in[4];
    const float* bg_flow   = (const float*)d_in[5];
    const float* ww_rgb    = (const float*)d_in[6];
    const float* bw_rgb    = (const float*)d_in[7];
    const float* gamma_rgb = (const float*)d_in[8];
    const float* beta_rgb  = (const float*)d_in[9];
    const float* ww_flow   = (const float*)d_in[10];
    const float* bw_flow   = (const float*)d_in[11];
    const float* gamma_flow= (const float*)d_in[12];
    const float* beta_flow = (const float*)d_in[13];
    float* out = (float*)d_out;
    float* ws  = (float*)d_ws;

    float* scale = ws;
    float* shift = ws + 1024;
    float* buf   = ws + 2048;

    // per-batch scratch floats: re+fe+ry+fy (4*CI*N) + S (N*N) + 4 stat vecs (4*N)
    const size_t perb = (size_t)4 * CI_ * N_ + (size_t)N_ * N_ + 4 * N_;
    size_t avail = ws_size / 4 - 2048;
    int nb = (int)(avail / perb);
    if (nb > B_) nb = B_;
    if (nb < 1) nb = 1;

    float* re   = buf;
    float* fe   = re + (size_t)nb * CI_ * N_;
    float* S    = fe + (size_t)nb * CI_ * N_;
    float* ry   = S  + (size_t)nb * N_ * N_;
    float* fy   = ry + (size_t)nb * CI_ * N_;
    float* rmax = fy + (size_t)nb * CI_ * N_;
    float* rinv = rmax + (size_t)nb * N_;
    float* cmax = rinv + (size_t)nb * N_;
    float* cinv = cmax + (size_t)nb * N_;

    dim3 thr(16, 16);
    for (int b0 = 0; b0 < B_; b0 += nb) {
        int bc = (B_ - b0 < nb) ? (B_ - b0) : nb;
        k_embed<<<dim3(16, 4, bc * 2), thr, 0, stream>>>(
            rgb, flow, wg_rgb, bg_rgb, wg_flow, bg_flow, re, fe, b0);
        k_scores<<<dim3(16, 16, bc), thr, 0, stream>>>(re, fe, S);
        k_rowstats<<<dim3(bc * N_), dim3(256), 0, stream>>>(S, rmax, rinv);
        k_colstats<<<dim3(4, bc), dim3(256), 0, stream>>>(S, cmax, cinv);
        k_rgby<<<dim3(16, 4, bc), thr, 0, stream>>>(fe, S, rmax, rinv, ry);
        k_flowy<<<dim3(16, 4, bc), thr, 0, stream>>>(re, S, cmax, cinv, fy);
        k_conv2<<<dim3(16, 8, bc * 2), thr, 0, stream>>>(
            ry, fy, ww_rgb, bw_rgb, ww_flow, bw_flow, out, b0);
    }
    k_bnstats<<<dim3(1024), dim3(256), 0, stream>>>(
        out, gamma_rgb, beta_rgb, gamma_flow, beta_flow, scale, shift);
    k_bnapply<<<dim3((2 * B_ * C_ * N_ / 4) / 256), dim3(256), 0, stream>>>(
        out, rgb, flow, scale, shift);
}

// Round 2
// 364.910 us; speedup vs baseline: 2.4551x; 2.4551x over previous
//
#include <hip/hip_runtime.h>

#define B_   16
#define C_   512
#define CI_  256
#define N_   1024        // H*W
#define EPS_ 1e-5f

typedef short bf16x8 __attribute__((ext_vector_type(8)));
typedef float f32x4  __attribute__((ext_vector_type(4)));

__device__ __forceinline__ short f2bf(float x) {
    union { float f; unsigned u; } un; un.f = x;
    unsigned r = un.u + 0x7fff + ((un.u >> 16) & 1);   // RNE
    return (short)(r >> 16);
}

// ---------------------------------------------------------------------------
// NT bf16 MFMA GEMM: O[r][c] = sum_k A[r][k]*B[c][k]. 128x128 tile, BK=64,
// 256 threads = 4 waves (2x2 quadrants of 64x64), 4x4 frags of 16x16x32.
// LDS: [row][8 chunks of 8 bf16], chunk XOR-swizzled by (row&7).
// OUTBF16: 0=fp32 out, 1=bf16 out. BIASMODE: 0 none, 1 row-bias, 2 col-bias.
// ---------------------------------------------------------------------------
template<int OUTBF16, int BIASMODE>
__device__ __forceinline__ void gemm_nt_dev(
    const short* __restrict__ A, const short* __restrict__ B,
    void* __restrict__ Optr, const float* __restrict__ bias,
    int K, int ldO)
{
    __shared__ bf16x8 As[128 * 8];
    __shared__ bf16x8 Bs[128 * 8];
    const int t = threadIdx.x;
    const int w = t >> 6, l = t & 63;
    const int wr = (w >> 1) * 64, wc = (w & 1) * 64;
    const int rowB = blockIdx.y * 128;
    const int colB = blockIdx.x * 128;
    const int lr = l & 15, lk = l >> 4;

    f32x4 acc[4][4];
#pragma unroll
    for (int mi = 0; mi < 4; ++mi)
#pragma unroll
        for (int nj = 0; nj < 4; ++nj) {
            acc[mi][nj][0] = 0.f; acc[mi][nj][1] = 0.f;
            acc[mi][nj][2] = 0.f; acc[mi][nj][3] = 0.f;
        }

    for (int k0 = 0; k0 < K; k0 += 64) {
#pragma unroll
        for (int it = 0; it < 4; ++it) {
            int idx = it * 256 + t;
            int r = idx >> 3, c = idx & 7;
            As[r * 8 + (c ^ (r & 7))] =
                *(const bf16x8*)(A + (size_t)(rowB + r) * K + k0 + c * 8);
            Bs[r * 8 + (c ^ (r & 7))] =
                *(const bf16x8*)(B + (size_t)(colB + r) * K + k0 + c * 8);
        }
        __syncthreads();
#pragma unroll
        for (int ks = 0; ks < 2; ++ks) {
            bf16x8 af[4], bfr[4];
#pragma unroll
            for (int mi = 0; mi < 4; ++mi) {
                int r = wr + mi * 16 + lr;
                af[mi] = As[r * 8 + ((ks * 4 + lk) ^ (r & 7))];
            }
#pragma unroll
            for (int nj = 0; nj < 4; ++nj) {
                int c = wc + nj * 16 + lr;
                bfr[nj] = Bs[c * 8 + ((ks * 4 + lk) ^ (c & 7))];
            }
#pragma unroll
            for (int mi = 0; mi < 4; ++mi)
#pragma unroll
                for (int nj = 0; nj < 4; ++nj)
                    acc[mi][nj] = __builtin_amdgcn_mfma_f32_16x16x32_bf16(
                        af[mi], bfr[nj], acc[mi][nj], 0, 0, 0);
        }
        __syncthreads();
    }

#pragma unroll
    for (int mi = 0; mi < 4; ++mi) {
#pragma unroll
        for (int q = 0; q < 4; ++q) {
            int rg = rowB + wr + mi * 16 + lk * 4 + q;
            float bvr = (BIASMODE == 1) ? bias[rg] : 0.f;
#pragma unroll
            for (int nj = 0; nj < 4; ++nj) {
                int cg = colB + wc + nj * 16 + lr;
                float v = acc[mi][nj][q];
                if (BIASMODE == 1) v += bvr;
                if (BIASMODE == 2) v += bias[cg];
                if (OUTBF16)
                    ((short*)Optr)[(size_t)rg * ldO + cg] = f2bf(v);
                else
                    ((float*)Optr)[(size_t)rg * ldO + cg] = v;
            }
        }
    }
}

// Wrappers -------------------------------------------------------------------
__global__ __launch_bounds__(256) void k_gemm_embed(
    const short* __restrict__ Xt, const short* __restrict__ wgbf,
    short* __restrict__ ref_t, const float* __restrict__ bg_rgb,
    const float* __restrict__ bg_flow)
{
    int z = blockIdx.z, st = z & 1;
    gemm_nt_dev<1, 2>(Xt + (size_t)z * N_ * C_, wgbf + (size_t)st * CI_ * C_,
                      ref_t + (size_t)z * N_ * CI_,
                      st ? bg_flow : bg_rgb, C_, CI_);
}

__global__ __launch_bounds__(256) void k_gemm_scores(
    const short* __restrict__ ref_t, float* __restrict__ S)
{
    int z = blockIdx.z;
    gemm_nt_dev<0, 0>(ref_t + (size_t)(2 * z) * N_ * CI_,
                      ref_t + (size_t)(2 * z + 1) * N_ * CI_,
                      S + (size_t)z * N_ * N_, nullptr, CI_, N_);
}

// sel=0: rgb_y (A=P,  B=fe_n=refn[2z+1], O=y[2z])
// sel=1: flow_y (A=Qt, B=re_n=refn[2z],  O=y[2z+1])
__global__ __launch_bounds__(256) void k_gemm_pv(
    const short* __restrict__ Pb, const short* __restrict__ refn,
    short* __restrict__ ybuf, int sel)
{
    int z = blockIdx.z;
    const short* Bp = refn + (size_t)(2 * z + (sel ^ 1)) * CI_ * N_;
    short* Op = ybuf + (size_t)(2 * z + sel) * N_ * CI_;
    gemm_nt_dev<1, 0>(Pb + (size_t)z * N_ * N_, Bp, Op, nullptr, N_, CI_);
}

__global__ __launch_bounds__(256) void k_gemm_conv2(
    const short* __restrict__ ybuf, const short* __restrict__ wwbf,
    float* __restrict__ out, const float* __restrict__ bw_rgb,
    const float* __restrict__ bw_flow, int b0)
{
    int z = blockIdx.z, lb = z >> 1, st = z & 1;
    const short* Bp = ybuf + (size_t)z * N_ * CI_;
    const short* Ap = wwbf + (size_t)st * C_ * CI_;
    float* Op = out + ((size_t)st * B_ + (b0 + lb)) * C_ * N_;
    gemm_nt_dev<0, 1>(Ap, Bp, Op, st ? bw_flow : bw_rgb, CI_, N_);
}

// Memory passes --------------------------------------------------------------
// fp32 [C][N] -> bf16 [N][C]
__global__ __launch_bounds__(256) void k_tin(
    const float* __restrict__ rgb, const float* __restrict__ flow,
    short* __restrict__ Xt, int b0)
{
    int z = blockIdx.z, lb = z >> 1, st = z & 1;
    const float* X = (st ? flow : rgb) + (size_t)(b0 + lb) * C_ * N_;
    short* O = Xt + (size_t)z * N_ * C_;
    __shared__ float tl[32][33];
    int n0 = blockIdx.x * 32, c0 = blockIdx.y * 32;
    int tx = threadIdx.x & 31, ty = threadIdx.x >> 5;
#pragma unroll
    for (int j = 0; j < 4; ++j)
        tl[ty + j * 8][tx] = X[(size_t)(c0 + ty + j * 8) * N_ + n0 + tx];
    __syncthreads();
#pragma unroll
    for (int j = 0; j < 4; ++j)
        O[(size_t)(n0 + ty + j * 8) * C_ + c0 + tx] = f2bf(tl[tx][ty + j * 8]);
}

// bf16 [N][CI] -> bf16 [CI][N]
__global__ __launch_bounds__(256) void k_tbf(
    const short* __restrict__ ref_t, short* __restrict__ ref_n)
{
    int z = blockIdx.z;
    const short* I = ref_t + (size_t)z * N_ * CI_;
    short* O = ref_n + (size_t)z * CI_ * N_;
    __shared__ short tl[32][34];
    int n0 = blockIdx.x * 32, i0 = blockIdx.y * 32;
    int tx = threadIdx.x & 31, ty = threadIdx.x >> 5;
#pragma unroll
    for (int j = 0; j < 4; ++j)
        tl[ty + j * 8][tx] = I[(size_t)(n0 + ty + j * 8) * CI_ + i0 + tx];
    __syncthreads();
#pragma unroll
    for (int j = 0; j < 4; ++j)
        O[(size_t)(i0 + ty + j * 8) * N_ + n0 + tx] = tl[tx][ty + j * 8];
}

__global__ __launch_bounds__(256) void k_castw(
    const float* __restrict__ wgr, const float* __restrict__ wgf,
    const float* __restrict__ wwr, const float* __restrict__ wwf,
    short* __restrict__ wgbf, short* __restrict__ wwbf)
{
    int which = blockIdx.y;
    size_t e = ((size_t)blockIdx.x * 256 + threadIdx.x) * 4;
    const float* src = which == 0 ? wgr : which == 1 ? wgf : which == 2 ? wwr : wwf;
    short* dst = which < 2 ? wgbf + (size_t)which * CI_ * C_
                           : wwbf + (size_t)(which - 2) * C_ * CI_;
    float4 v = *(const float4*)(src + e);
    short4 o; o.x = f2bf(v.x); o.y = f2bf(v.y); o.z = f2bf(v.z); o.w = f2bf(v.w);
    *(short4*)(dst + e) = o;
}

// row softmax stats over m (last dim)
__global__ __launch_bounds__(256) void k_rowstats(
    const float* __restrict__ S, float* __restrict__ rmax, float* __restrict__ rinv)
{
    const int row = blockIdx.x;
    const float* Sr = S + (size_t)row * N_;
    const int t = threadIdx.x;
    float v[4];
    float mx = -1e30f;
#pragma unroll
    for (int r = 0; r < 4; ++r) { v[r] = Sr[t + r * 256]; mx = fmaxf(mx, v[r]); }
#pragma unroll
    for (int off = 32; off > 0; off >>= 1) mx = fmaxf(mx, __shfl_down(mx, off));
    __shared__ float red[8];
    if ((t & 63) == 0) red[t >> 6] = mx;
    __syncthreads();
    mx = fmaxf(fmaxf(red[0], red[1]), fmaxf(red[2], red[3]));
    float s = 0.f;
#pragma unroll
    for (int r = 0; r < 4; ++r) s += __expf(v[r] - mx);
#pragma unroll
    for (int off = 32; off > 0; off >>= 1) s += __shfl_down(s, off);
    if ((t & 63) == 0) red[4 + (t >> 6)] = s;
    __syncthreads();
    if (t == 0) {
        float tot = red[4] + red[5] + red[6] + red[7];
        rmax[row] = mx;
        rinv[row] = 1.0f / tot;
    }
}

// column softmax stats, two-phase
__global__ __launch_bounds__(256) void k_colpart(
    const float* __restrict__ S, float* __restrict__ pmax, float* __restrict__ psum)
{
    int z = blockIdx.z, seg = blockIdx.y;
    int m = blockIdx.x * 256 + threadIdx.x;
    const float* Sb = S + (size_t)z * N_ * N_ + (size_t)seg * 256 * N_;
    float mx = -1e30f, sum = 0.f;
    for (int n = 0; n < 256; ++n) {
        float v = Sb[(size_t)n * N_ + m];
        float nmx = fmaxf(mx, v);
        sum = sum * __expf(mx - nmx) + __expf(v - nmx);
        mx = nmx;
    }
    pmax[(size_t)(z * 4 + seg) * N_ + m] = mx;
    psum[(size_t)(z * 4 + seg) * N_ + m] = sum;
}

__global__ __launch_bounds__(256) void k_colfin(
    const float* __restrict__ pmax, const float* __restrict__ psum,
    float* __restrict__ cmax, float* __restrict__ cinv)
{
    int z = blockIdx.y;
    int m = blockIdx.x * 256 + threadIdx.x;
    float M = -1e30f;
#pragma unroll
    for (int s = 0; s < 4; ++s) M = fmaxf(M, pmax[(size_t)(z * 4 + s) * N_ + m]);
    float tot = 0.f;
#pragma unroll
    for (int s = 0; s < 4; ++s)
        tot += psum[(size_t)(z * 4 + s) * N_ + m] *
               __expf(pmax[(size_t)(z * 4 + s) * N_ + m] - M);
    cmax[(size_t)z * N_ + m] = M;
    cinv[(size_t)z * N_ + m] = 1.0f / tot;
}

// P[n][m] = bf16(exp(S-rmax[n])*rinv[n])
__global__ __launch_bounds__(256) void k_prow(
    const float* __restrict__ S, const float* __restrict__ rmax,
    const float* __restrict__ rinv, short* __restrict__ P)
{
    int z = blockIdx.y;
    size_t e = ((size_t)blockIdx.x * 256 + threadIdx.x) * 4;
    int n = (int)(e >> 10);
    float mm = rmax[(size_t)z * N_ + n], ri = rinv[(size_t)z * N_ + n];
    float4 v = *(const float4*)(S + (size_t)z * N_ * N_ + e);
    short4 o;
    o.x = f2bf(__expf(v.x - mm) * ri);
    o.y = f2bf(__expf(v.y - mm) * ri);
    o.z = f2bf(__expf(v.z - mm) * ri);
    o.w = f2bf(__expf(v.w - mm) * ri);
    *(short4*)(P + (size_t)z * N_ * N_ + e) = o;
}

// Qt[m][n] = bf16(exp(S[n][m]-cmax[m])*cinv[m])  (transpose via LDS)
__global__ __launch_bounds__(256) void k_qcolt(
    const float* __restrict__ S, const float* __restrict__ cmax,
    const float* __restrict__ cinv, short* __restrict__ Qt)
{
    int z = blockIdx.z;
    int n0 = blockIdx.x * 32, m0 = blockIdx.y * 32;
    __shared__ short tl[32][34];
    int tx = threadIdx.x & 31, ty = threadIdx.x >> 5;
    float cm = cmax[(size_t)z * N_ + m0 + tx];
    float ci = cinv[(size_t)z * N_ + m0 + tx];
#pragma unroll
    for (int j = 0; j < 4; ++j) {
        float v = S[(size_t)z * N_ * N_ + (size_t)(n0 + ty + j * 8) * N_ + m0 + tx];
        tl[ty + j * 8][tx] = f2bf(__expf(v - cm) * ci);
    }
    __syncthreads();
#pragma unroll
    for (int j = 0; j < 4; ++j)
        Qt[(size_t)z * N_ * N_ + (size_t)(m0 + ty + j * 8) * N_ + n0 + tx] =
            tl[tx][ty + j * 8];
}

// BN -------------------------------------------------------------------------
__global__ __launch_bounds__(256) void k_bnstats(
    const float* __restrict__ zall,
    const float* __restrict__ gamma_rgb, const float* __restrict__ beta_rgb,
    const float* __restrict__ gamma_flow, const float* __restrict__ beta_flow,
    float* __restrict__ scale, float* __restrict__ shift)
{
    const int st = blockIdx.x >> 9;
    const int c = blockIdx.x & 511;
    const float* z0 = zall + (size_t)st * B_ * C_ * N_ + (size_t)c * N_;
    const int t = threadIdx.x;
    float s = 0.f, ss = 0.f;
    for (int b = 0; b < B_; ++b) {
        const float* zb = z0 + (size_t)b * C_ * N_;
        for (int n = t; n < N_; n += 256) {
            float v = zb[n];
            s += v; ss += v * v;
        }
    }
#pragma unroll
    for (int off = 32; off > 0; off >>= 1) {
        s += __shfl_down(s, off);
        ss += __shfl_down(ss, off);
    }
    __shared__ float rs[4], rss[4];
    if ((t & 63) == 0) { rs[t >> 6] = s; rss[t >> 6] = ss; }
    __syncthreads();
    if (t == 0) {
        float S1 = rs[0] + rs[1] + rs[2] + rs[3];
        float S2 = rss[0] + rss[1] + rss[2] + rss[3];
        const float inv_cnt = 1.0f / (float)(B_ * N_);
        float mean = S1 * inv_cnt;
        float var = S2 * inv_cnt - mean * mean;
        float g = st ? gamma_flow[c] : gamma_rgb[c];
        float be = st ? beta_flow[c] : beta_rgb[c];
        float sc = g * rsqrtf(var + EPS_);
        scale[st * C_ + c] = sc;
        shift[st * C_ + c] = be - mean * sc;
    }
}

__global__ __launch_bounds__(256) void k_bnapply(
    float* __restrict__ out, const float* __restrict__ rgb,
    const float* __restrict__ flow, const float* __restrict__ scale,
    const float* __restrict__ shift)
{
    const size_t idx = (size_t)blockIdx.x * 256 + threadIdx.x;
    const size_t e = idx * 4;
    const size_t half = (size_t)B_ * C_ * N_;
    const int st = e >= half;
    const size_t rem = e - (size_t)st * half;
    const int c = (int)((rem >> 10) & (C_ - 1));
    const float* x = (st ? flow : rgb) + rem;
    const float sc = scale[st * C_ + c];
    const float sh = shift[st * C_ + c];
    float4 z = *reinterpret_cast<const float4*>(out + e);
    float4 xv = *reinterpret_cast<const float4*>(x);
    float4 rr;
    rr.x = z.x * sc + sh + xv.x;
    rr.y = z.y * sc + sh + xv.y;
    rr.z = z.z * sc + sh + xv.z;
    rr.w = z.w * sc + sh + xv.w;
    *reinterpret_cast<float4*>(out + e) = rr;
}

// ---------------------------------------------------------------------------
extern "C" void kernel_launch(void* const* d_in, const int* in_sizes, int n_in,
                              void* d_out, int out_size, void* d_ws, size_t ws_size,
                              hipStream_t stream)
{
    const float* rgb        = (const float*)d_in[0];
    const float* flow       = (const float*)d_in[1];
    const float* wg_rgb     = (const float*)d_in[2];
    const float* bg_rgb     = (const float*)d_in[3];
    const float* wg_flow    = (const float*)d_in[4];
    const float* bg_flow    = (const float*)d_in[5];
    const float* ww_rgb     = (const float*)d_in[6];
    const float* bw_rgb     = (const float*)d_in[7];
    const float* gamma_rgb  = (const float*)d_in[8];
    const float* beta_rgb   = (const float*)d_in[9];
    const float* ww_flow    = (const float*)d_in[10];
    const float* bw_flow    = (const float*)d_in[11];
    const float* gamma_flow = (const float*)d_in[12];
    const float* beta_flow  = (const float*)d_in[13];
    float* out = (float*)d_out;

    char* p = (char*)d_ws;
    short* wgbf = (short*)p;            p += (size_t)2 * CI_ * C_ * 2;
    short* wwbf = (short*)p;            p += (size_t)2 * C_ * CI_ * 2;
    float* scale = (float*)p;           p += 1024 * 4;
    float* shift = (float*)p;           p += 1024 * 4;

    const size_t fixed = (size_t)(p - (char*)d_ws);
    // per-batch bytes: Xt 2MB + ref_t 1MB + ref_n 1MB + ybuf 1MB + S 4MB
    //                + P 2MB + Qt 2MB + stats 48KB
    const size_t perb = (size_t)2097152 + 3 * 1048576 + 4194304 + 2 * 2097152 + 49152;
    int nb = (int)((ws_size - fixed) / perb);
    if (nb > B_) nb = B_;
    if (nb < 1) nb = 1;

    short* Xt    = (short*)p;           p += (size_t)nb * 2097152;
    short* ref_t = (short*)p;           p += (size_t)nb * 1048576;
    short* ref_n = (short*)p;           p += (size_t)nb * 1048576;
    short* ybuf  = (short*)p;           p += (size_t)nb * 1048576;
    float* S     = (float*)p;           p += (size_t)nb * 4194304;
    short* P     = (short*)p;           p += (size_t)nb * 2097152;
    short* Qt    = (short*)p;           p += (size_t)nb * 2097152;
    float* rmax  = (float*)p;           p += (size_t)nb * 4096;
    float* rinv  = (float*)p;           p += (size_t)nb * 4096;
    float* cmax  = (float*)p;           p += (size_t)nb * 4096;
    float* cinv  = (float*)p;           p += (size_t)nb * 4096;
    float* pmax  = (float*)p;           p += (size_t)nb * 16384;
    float* psum  = (float*)p;           p += (size_t)nb * 16384;

    k_castw<<<dim3(128, 4), dim3(256), 0, stream>>>(
        wg_rgb, wg_flow, ww_rgb, ww_flow, wgbf, wwbf);

    for (int b0 = 0; b0 < B_; b0 += nb) {
        int bc = (B_ - b0 < nb) ? (B_ - b0) : nb;
        k_tin<<<dim3(32, 16, bc * 2), dim3(256), 0, stream>>>(rgb, flow, Xt, b0);
        k_gemm_embed<<<dim3(2, 8, bc * 2), dim3(256), 0, stream>>>(
            Xt, wgbf, ref_t, bg_rgb, bg_flow);
        k_gemm_scores<<<dim3(8, 8, bc), dim3(256), 0, stream>>>(ref_t, S);
        k_rowstats<<<dim3(bc * N_), dim3(256), 0, stream>>>(S, rmax, rinv);
        k_colpart<<<dim3(4, 4, bc), dim3(256), 0, stream>>>(S, pmax, psum);
        k_colfin<<<dim3(4, bc), dim3(256), 0, stream>>>(pmax, psum, cmax, cinv);
        k_prow<<<dim3(1024, bc), dim3(256), 0, stream>>>(S, rmax, rinv, P);
        k_qcolt<<<dim3(32, 32, bc), dim3(256), 0, stream>>>(S, cmax, cinv, Qt);
        k_tbf<<<dim3(32, 8, bc * 2), dim3(256), 0, stream>>>(ref_t, ref_n);
        k_gemm_pv<<<dim3(2, 8, bc), dim3(256), 0, stream>>>(P, ref_n, ybuf, 0);
        k_gemm_pv<<<dim3(2, 8, bc), dim3(256), 0, stream>>>(Qt, ref_n, ybuf, 1);
        k_gemm_conv2<<<dim3(8, 4, bc * 2), dim3(256), 0, stream>>>(
            ybuf, wwbf, out, bw_rgb, bw_flow, b0);
    }
    k_bnstats<<<dim3(1024), dim3(256), 0, stream>>>(
        out, gamma_rgb, beta_rgb, gamma_flow, beta_flow, scale, shift);
    k_bnapply<<<dim3((2 * B_ * C_ * N_ / 4) / 256), dim3(256), 0, stream>>>(
        out, rgb, flow, scale, shift);
}

// Round 3
// 338.668 us; speedup vs baseline: 2.6453x; 1.0775x over previous
//
#include <hip/hip_runtime.h>

#define B_   16
#define C_   512
#define CI_  256
#define N_   1024        // H*W
#define EPS_ 1e-5f

typedef short bf16x8 __attribute__((ext_vector_type(8)));
typedef float f32x4  __attribute__((ext_vector_type(4)));

__device__ __forceinline__ short f2bf(float x) {
    union { float f; unsigned u; } un; un.f = x;
    unsigned r = un.u + 0x7fff + ((un.u >> 16) & 1);   // RNE
    return (short)(r >> 16);
}
__device__ __forceinline__ float bf2f(short x) {
    union { unsigned u; float f; } un;
    un.u = ((unsigned)(unsigned short)x) << 16;
    return un.f;
}

// MFMA inner tile: 128x128, 4 waves (2x2 of 64x64), 16x16x32 bf16 frags.
// As/Bs: [row][8 chunks of bf16x8], chunk XOR-swizzled by (row&7).
__device__ __forceinline__ void mfma_tile(
    const bf16x8* As, const bf16x8* Bs, int wr, int wc, int lr, int lk,
    f32x4 acc[4][4])
{
#pragma unroll
    for (int ks = 0; ks < 2; ++ks) {
        bf16x8 af[4], bfr[4];
#pragma unroll
        for (int mi = 0; mi < 4; ++mi) {
            int r = wr + mi * 16 + lr;
            af[mi] = As[r * 8 + ((ks * 4 + lk) ^ (r & 7))];
        }
#pragma unroll
        for (int nj = 0; nj < 4; ++nj) {
            int c = wc + nj * 16 + lr;
            bfr[nj] = Bs[c * 8 + ((ks * 4 + lk) ^ (c & 7))];
        }
#pragma unroll
        for (int mi = 0; mi < 4; ++mi)
#pragma unroll
            for (int nj = 0; nj < 4; ++nj)
                acc[mi][nj] = __builtin_amdgcn_mfma_f32_16x16x32_bf16(
                    af[mi], bfr[nj], acc[mi][nj], 0, 0, 0);
    }
}

#define ZERO_ACC(acc) \
    _Pragma("unroll") for (int mi = 0; mi < 4; ++mi) \
    _Pragma("unroll") for (int nj = 0; nj < 4; ++nj) { \
        acc[mi][nj][0]=0.f; acc[mi][nj][1]=0.f; acc[mi][nj][2]=0.f; acc[mi][nj][3]=0.f; }

// ---------------------------------------------------------------------------
// K1: embed GEMM. O[n][i] = sum_c Xt[n][c]*wg[i][c] + bg[i], bf16 out.
__global__ __launch_bounds__(256) void k_embed(
    const short* __restrict__ Xt, const short* __restrict__ wgbf,
    short* __restrict__ ref_t, const float* __restrict__ bg_rgb,
    const float* __restrict__ bg_flow)
{
    const int z = blockIdx.z, st = z & 1;
    const short* A = Xt + (size_t)z * N_ * C_;
    const short* Bp = wgbf + (size_t)st * CI_ * C_;
    const float* bias = st ? bg_flow : bg_rgb;
    short* O = ref_t + (size_t)z * N_ * CI_;
    const int rowB = blockIdx.y * 128, colB = blockIdx.x * 128;
    __shared__ bf16x8 As[128 * 8], Bs[128 * 8];
    const int t = threadIdx.x, w = t >> 6, l = t & 63;
    const int wr = (w >> 1) * 64, wc = (w & 1) * 64, lr = l & 15, lk = l >> 4;
    f32x4 acc[4][4]; ZERO_ACC(acc);

    for (int k0 = 0; k0 < C_; k0 += 64) {
#pragma unroll
        for (int it = 0; it < 4; ++it) {
            int idx = it * 256 + t;
            int r = idx >> 3, c = idx & 7;
            As[r * 8 + (c ^ (r & 7))] =
                *(const bf16x8*)(A + (size_t)(rowB + r) * C_ + k0 + c * 8);
            Bs[r * 8 + (c ^ (r & 7))] =
                *(const bf16x8*)(Bp + (size_t)(colB + r) * C_ + k0 + c * 8);
        }
        __syncthreads();
        mfma_tile(As, Bs, wr, wc, lr, lk, acc);
        __syncthreads();
    }
#pragma unroll
    for (int mi = 0; mi < 4; ++mi)
#pragma unroll
        for (int q = 0; q < 4; ++q) {
            int rg = rowB + wr + mi * 16 + lk * 4 + q;
#pragma unroll
            for (int nj = 0; nj < 4; ++nj) {
                int cg = colB + wc + nj * 16 + lr;
                O[(size_t)rg * CI_ + cg] = f2bf(acc[mi][nj][q] + bias[cg]);
            }
        }
}

// K2: scores GEMM + fused row/col softmax partial stats.
__global__ __launch_bounds__(256) void k_scores(
    const short* __restrict__ ref_t, float* __restrict__ S,
    float* __restrict__ pRmax, float* __restrict__ pRsum,
    float* __restrict__ pCmax, float* __restrict__ pCsum)
{
    const int z = blockIdx.z;
    const short* A = ref_t + (size_t)(2 * z) * N_ * CI_;
    const short* Bp = ref_t + (size_t)(2 * z + 1) * N_ * CI_;
    float* So = S + (size_t)z * N_ * N_;
    const int rowB = blockIdx.y * 128, colB = blockIdx.x * 128;
    __shared__ bf16x8 As[128 * 8], Bs[128 * 8];
    const int t = threadIdx.x, w = t >> 6, l = t & 63;
    const int wr = (w >> 1) * 64, wc = (w & 1) * 64, lr = l & 15, lk = l >> 4;
    f32x4 acc[4][4]; ZERO_ACC(acc);

    for (int k0 = 0; k0 < CI_; k0 += 64) {
#pragma unroll
        for (int it = 0; it < 4; ++it) {
            int idx = it * 256 + t;
            int r = idx >> 3, c = idx & 7;
            As[r * 8 + (c ^ (r & 7))] =
                *(const bf16x8*)(A + (size_t)(rowB + r) * CI_ + k0 + c * 8);
            Bs[r * 8 + (c ^ (r & 7))] =
                *(const bf16x8*)(Bp + (size_t)(colB + r) * CI_ + k0 + c * 8);
        }
        __syncthreads();
        mfma_tile(As, Bs, wr, wc, lr, lk, acc);
        __syncthreads();
    }
    // write S fp32
#pragma unroll
    for (int mi = 0; mi < 4; ++mi)
#pragma unroll
        for (int q = 0; q < 4; ++q) {
            int rg = rowB + wr + mi * 16 + lk * 4 + q;
#pragma unroll
            for (int nj = 0; nj < 4; ++nj)
                So[(size_t)rg * N_ + colB + wc + nj * 16 + lr] = acc[mi][nj][q];
        }

    __shared__ float redM[128][2], redS2[128][2];
    // ---- row partials (reduce over this block's 128 cols) ----
    float Mrow[4][4];
#pragma unroll
    for (int mi = 0; mi < 4; ++mi)
#pragma unroll
        for (int q = 0; q < 4; ++q) {
            float mx = fmaxf(fmaxf(acc[mi][0][q], acc[mi][1][q]),
                             fmaxf(acc[mi][2][q], acc[mi][3][q]));
#pragma unroll
            for (int d = 1; d < 16; d <<= 1) mx = fmaxf(mx, __shfl_xor(mx, d));
            if (lr == 0) redM[wr + mi * 16 + lk * 4 + q][w & 1] = mx;
        }
    __syncthreads();
#pragma unroll
    for (int mi = 0; mi < 4; ++mi)
#pragma unroll
        for (int q = 0; q < 4; ++q) {
            int rl = wr + mi * 16 + lk * 4 + q;
            Mrow[mi][q] = fmaxf(redM[rl][0], redM[rl][1]);
        }
#pragma unroll
    for (int mi = 0; mi < 4; ++mi)
#pragma unroll
        for (int q = 0; q < 4; ++q) {
            float s = 0.f;
#pragma unroll
            for (int nj = 0; nj < 4; ++nj)
                s += __expf(acc[mi][nj][q] - Mrow[mi][q]);
#pragma unroll
            for (int d = 1; d < 16; d <<= 1) s += __shfl_xor(s, d);
            if (lr == 0) redS2[wr + mi * 16 + lk * 4 + q][w & 1] = s;
        }
    __syncthreads();
    if (t < 128) {
        float M = fmaxf(redM[t][0], redM[t][1]);
        float sm = redS2[t][0] + redS2[t][1];
        size_t o = (((size_t)z * 8 + blockIdx.x) << 10) + rowB + t;
        pRmax[o] = M; pRsum[o] = sm;
    }
    __syncthreads();
    // ---- col partials (reduce over this block's 128 rows) ----
    float Mcol[4];
#pragma unroll
    for (int nj = 0; nj < 4; ++nj) {
        float mx = -1e30f;
#pragma unroll
        for (int mi = 0; mi < 4; ++mi)
#pragma unroll
            for (int q = 0; q < 4; ++q) mx = fmaxf(mx, acc[mi][nj][q]);
        mx = fmaxf(mx, __shfl_xor(mx, 16));
        mx = fmaxf(mx, __shfl_xor(mx, 32));
        if (lk == 0) redM[wc + nj * 16 + lr][w >> 1] = mx;
    }
    __syncthreads();
#pragma unroll
    for (int nj = 0; nj < 4; ++nj) {
        int cl = wc + nj * 16 + lr;
        Mcol[nj] = fmaxf(redM[cl][0], redM[cl][1]);
    }
#pragma unroll
    for (int nj = 0; nj < 4; ++nj) {
        float s = 0.f;
#pragma unroll
        for (int mi = 0; mi < 4; ++mi)
#pragma unroll
            for (int q = 0; q < 4; ++q)
                s += __expf(acc[mi][nj][q] - Mcol[nj]);
        s += __shfl_xor(s, 16);
        s += __shfl_xor(s, 32);
        if (lk == 0) redS2[wc + nj * 16 + lr][w >> 1] = s;
    }
    __syncthreads();
    if (t < 128) {
        float M = fmaxf(redM[t][0], redM[t][1]);
        float sm = redS2[t][0] + redS2[t][1];
        size_t o = (((size_t)z * 8 + blockIdx.y) << 10) + colB + t;
        pCmax[o] = M; pCsum[o] = sm;
    }
}

// K3: combine 8 partials -> rmax/rinv (rows) and cmax/cinv (cols).
__global__ __launch_bounds__(256) void k_sfin(
    const float* __restrict__ pRmax, const float* __restrict__ pRsum,
    const float* __restrict__ pCmax, const float* __restrict__ pCsum,
    float* __restrict__ rmax, float* __restrict__ rinv,
    float* __restrict__ cmax, float* __restrict__ cinv)
{
    const int z = blockIdx.y;
    const int part = blockIdx.x;          // 0..3 rows, 4..7 cols
    const int isCol = part >> 2;
    const int n = (part & 3) * 256 + threadIdx.x;
    const float* pM = (isCol ? pCmax : pRmax) + (((size_t)z * 8) << 10) + n;
    const float* pS = (isCol ? pCsum : pRsum) + (((size_t)z * 8) << 10) + n;
    float M = -1e30f;
#pragma unroll
    for (int j = 0; j < 8; ++j) M = fmaxf(M, pM[(size_t)j << 10]);
    float s = 0.f;
#pragma unroll
    for (int j = 0; j < 8; ++j)
        s += pS[(size_t)j << 10] * __expf(pM[(size_t)j << 10] - M);
    float* oM = isCol ? cmax : rmax;
    float* oI = isCol ? cinv : rinv;
    oM[(size_t)z * N_ + n] = M;
    oI[(size_t)z * N_ + n] = 1.f / s;
}

// K4: rgb PV. O[n][i] = sum_m P[n][m]*fe[i][m]; P from S on the fly.
__global__ __launch_bounds__(256) void k_pv_rgb(
    const float* __restrict__ S, const short* __restrict__ ref_n,
    const float* __restrict__ rmax, const float* __restrict__ rinv,
    short* __restrict__ ybuf)
{
    const int z = blockIdx.z;
    const float* Sb = S + (size_t)z * N_ * N_;
    const short* Bp = ref_n + (size_t)(2 * z + 1) * CI_ * N_;   // fe_n
    short* Op = ybuf + (size_t)(2 * z) * N_ * CI_;
    const int rowB = blockIdx.y * 128, colB = blockIdx.x * 128;
    __shared__ bf16x8 As[128 * 8], Bs[128 * 8];
    __shared__ float rm[128], ri[128];
    const int t = threadIdx.x, w = t >> 6, l = t & 63;
    const int wr = (w >> 1) * 64, wc = (w & 1) * 64, lr = l & 15, lk = l >> 4;
    if (t < 128) { rm[t] = rmax[(size_t)z * N_ + rowB + t];
                   ri[t] = rinv[(size_t)z * N_ + rowB + t]; }
    __syncthreads();
    f32x4 acc[4][4]; ZERO_ACC(acc);

    for (int k0 = 0; k0 < N_; k0 += 64) {
#pragma unroll
        for (int it = 0; it < 4; ++it) {
            int idx = it * 256 + t;
            int r = idx >> 3, c8 = idx & 7;
            const float* sp = Sb + (size_t)(rowB + r) * N_ + k0 + c8 * 8;
            float4 v0 = *(const float4*)sp;
            float4 v1 = *(const float4*)(sp + 4);
            float M = rm[r], iv = ri[r];
            bf16x8 pk;
            pk[0] = f2bf(__expf(v0.x - M) * iv); pk[1] = f2bf(__expf(v0.y - M) * iv);
            pk[2] = f2bf(__expf(v0.z - M) * iv); pk[3] = f2bf(__expf(v0.w - M) * iv);
            pk[4] = f2bf(__expf(v1.x - M) * iv); pk[5] = f2bf(__expf(v1.y - M) * iv);
            pk[6] = f2bf(__expf(v1.z - M) * iv); pk[7] = f2bf(__expf(v1.w - M) * iv);
            As[r * 8 + (c8 ^ (r & 7))] = pk;
            Bs[r * 8 + (c8 ^ (r & 7))] =
                *(const bf16x8*)(Bp + (size_t)(colB + r) * N_ + k0 + c8 * 8);
        }
        __syncthreads();
        mfma_tile(As, Bs, wr, wc, lr, lk, acc);
        __syncthreads();
    }
#pragma unroll
    for (int mi = 0; mi < 4; ++mi)
#pragma unroll
        for (int q = 0; q < 4; ++q) {
            int rg = rowB + wr + mi * 16 + lk * 4 + q;
#pragma unroll
            for (int nj = 0; nj < 4; ++nj)
                Op[(size_t)rg * CI_ + colB + wc + nj * 16 + lr] =
                    f2bf(acc[mi][nj][q]);
        }
}

// K5: flow PV. O[m][i] = sum_n Q[n][m]*re[i][n]; Q^T staged via LDS fp32 tile.
__global__ __launch_bounds__(256) void k_pv_flow(
    const float* __restrict__ S, const short* __restrict__ ref_n,
    const float* __restrict__ cmax, const float* __restrict__ cinv,
    short* __restrict__ ybuf)
{
    const int z = blockIdx.z;
    const float* Sb = S + (size_t)z * N_ * N_;
    const short* Bp = ref_n + (size_t)(2 * z) * CI_ * N_;       // re_n
    short* Op = ybuf + (size_t)(2 * z + 1) * N_ * CI_;
    const int rowB = blockIdx.y * 128;   // m
    const int colB = blockIdx.x * 128;   // i
    __shared__ float Ss[64 * 132];       // [n][m], pad 4 floats
    __shared__ bf16x8 As[128 * 8], Bs[128 * 8];
    __shared__ float cm[128], ci[128];
    const int t = threadIdx.x, w = t >> 6, l = t & 63;
    const int wr = (w >> 1) * 64, wc = (w & 1) * 64, lr = l & 15, lk = l >> 4;
    if (t < 128) { cm[t] = cmax[(size_t)z * N_ + rowB + t];
                   ci[t] = cinv[(size_t)z * N_ + rowB + t]; }
    __syncthreads();
    f32x4 acc[4][4]; ZERO_ACC(acc);

    for (int k0 = 0; k0 < N_; k0 += 64) {
        // stage1: coalesced S rows -> LDS fp32; stage B directly
#pragma unroll
        for (int it = 0; it < 8; ++it) {
            int idx = it * 256 + t;
            int rr = idx >> 5, c4 = idx & 31;
            *(float4*)(Ss + rr * 132 + c4 * 4) =
                *(const float4*)(Sb + (size_t)(k0 + rr) * N_ + rowB + c4 * 4);
        }
#pragma unroll
        for (int it = 0; it < 4; ++it) {
            int idx = it * 256 + t;
            int r = idx >> 3, c = idx & 7;
            Bs[r * 8 + (c ^ (r & 7))] =
                *(const bf16x8*)(Bp + (size_t)(colB + r) * N_ + k0 + c * 8);
        }
        __syncthreads();
        // stage2: transpose + softmax -> bf16 As
#pragma unroll
        for (int it = 0; it < 4; ++it) {
            int idx = it * 256 + t;
            int m = idx & 127, c8 = idx >> 7;
            float M = cm[m], iv = ci[m];
            bf16x8 pk;
#pragma unroll
            for (int j = 0; j < 8; ++j)
                pk[j] = f2bf(__expf(Ss[(c8 * 8 + j) * 132 + m] - M) * iv);
            As[m * 8 + (c8 ^ (m & 7))] = pk;
        }
        __syncthreads();
        mfma_tile(As, Bs, wr, wc, lr, lk, acc);
        __syncthreads();
    }
#pragma unroll
    for (int mi = 0; mi < 4; ++mi)
#pragma unroll
        for (int q = 0; q < 4; ++q) {
            int rg = rowB + wr + mi * 16 + lk * 4 + q;
#pragma unroll
            for (int nj = 0; nj < 4; ++nj)
                Op[(size_t)rg * CI_ + colB + wc + nj * 16 + lr] =
                    f2bf(acc[mi][nj][q]);
        }
}

// K6: conv2 GEMM -> bf16 z + fused BN partial stats (atomics).
__global__ __launch_bounds__(256) void k_conv2bn(
    const short* __restrict__ ybuf, const short* __restrict__ wwbf,
    short* __restrict__ zbuf, const float* __restrict__ bw_rgb,
    const float* __restrict__ bw_flow, float* __restrict__ bnsum,
    float* __restrict__ bnssq, int b0)
{
    const int z = blockIdx.z, lb = z >> 1, st = z & 1;
    const int gb = b0 + lb;
    const short* A = wwbf + (size_t)st * C_ * CI_;
    const short* Bp = ybuf + (size_t)z * N_ * CI_;
    const float* bias = st ? bw_flow : bw_rgb;
    short* O = zbuf + ((size_t)st * B_ + gb) * C_ * N_;
    const int rowB = blockIdx.y * 128;   // c
    const int colB = blockIdx.x * 128;   // n
    __shared__ bf16x8 As[128 * 8], Bs[128 * 8];
    const int t = threadIdx.x, w = t >> 6, l = t & 63;
    const int wr = (w >> 1) * 64, wc = (w & 1) * 64, lr = l & 15, lk = l >> 4;
    f32x4 acc[4][4]; ZERO_ACC(acc);

    for (int k0 = 0; k0 < CI_; k0 += 64) {
#pragma unroll
        for (int it = 0; it < 4; ++it) {
            int idx = it * 256 + t;
            int r = idx >> 3, c = idx & 7;
            As[r * 8 + (c ^ (r & 7))] =
                *(const bf16x8*)(A + (size_t)(rowB + r) * CI_ + k0 + c * 8);
            Bs[r * 8 + (c ^ (r & 7))] =
                *(const bf16x8*)(Bp + (size_t)(colB + r) * CI_ + k0 + c * 8);
        }
        __syncthreads();
        mfma_tile(As, Bs, wr, wc, lr, lk, acc);
        __syncthreads();
    }
    __shared__ float redS[128][2], redQ[128][2];
    float psum[4][4], pssq[4][4];
#pragma unroll
    for (int mi = 0; mi < 4; ++mi)
#pragma unroll
        for (int q = 0; q < 4; ++q) {
            int rg = rowB + wr + mi * 16 + lk * 4 + q;
            float bv = bias[rg];
            float s = 0.f, ss = 0.f;
#pragma unroll
            for (int nj = 0; nj < 4; ++nj) {
                short zb = f2bf(acc[mi][nj][q] + bv);
                O[(size_t)rg * N_ + colB + wc + nj * 16 + lr] = zb;
                float v = bf2f(zb);
                s += v; ss += v * v;
            }
            psum[mi][q] = s; pssq[mi][q] = ss;
        }
#pragma unroll
    for (int mi = 0; mi < 4; ++mi)
#pragma unroll
        for (int q = 0; q < 4; ++q) {
            float s = psum[mi][q], ss = pssq[mi][q];
#pragma unroll
            for (int d = 1; d < 16; d <<= 1) {
                s += __shfl_xor(s, d);
                ss += __shfl_xor(ss, d);
            }
            if (lr == 0) {
                redS[wr + mi * 16 + lk * 4 + q][w & 1] = s;
                redQ[wr + mi * 16 + lk * 4 + q][w & 1] = ss;
            }
        }
    __syncthreads();
    if (t < 128) {
        atomicAdd(&bnsum[st * C_ + rowB + t], redS[t][0] + redS[t][1]);
        atomicAdd(&bnssq[st * C_ + rowB + t], redQ[t][0] + redQ[t][1]);
    }
}

// Memory passes --------------------------------------------------------------
__global__ __launch_bounds__(256) void k_tin(
    const float* __restrict__ rgb, const float* __restrict__ flow,
    short* __restrict__ Xt, int b0)
{
    int z = blockIdx.z, lb = z >> 1, st = z & 1;
    const float* X = (st ? flow : rgb) + (size_t)(b0 + lb) * C_ * N_;
    short* O = Xt + (size_t)z * N_ * C_;
    __shared__ float tl[32][33];
    int n0 = blockIdx.x * 32, c0 = blockIdx.y * 32;
    int tx = threadIdx.x & 31, ty = threadIdx.x >> 5;
#pragma unroll
    for (int j = 0; j < 4; ++j)
        tl[ty + j * 8][tx] = X[(size_t)(c0 + ty + j * 8) * N_ + n0 + tx];
    __syncthreads();
#pragma unroll
    for (int j = 0; j < 4; ++j)
        O[(size_t)(n0 + ty + j * 8) * C_ + c0 + tx] = f2bf(tl[tx][ty + j * 8]);
}

__global__ __launch_bounds__(256) void k_tbf(
    const short* __restrict__ ref_t, short* __restrict__ ref_n)
{
    int z = blockIdx.z;
    const short* I = ref_t + (size_t)z * N_ * CI_;
    short* O = ref_n + (size_t)z * CI_ * N_;
    __shared__ short tl[32][34];
    int n0 = blockIdx.x * 32, i0 = blockIdx.y * 32;
    int tx = threadIdx.x & 31, ty = threadIdx.x >> 5;
#pragma unroll
    for (int j = 0; j < 4; ++j)
        tl[ty + j * 8][tx] = I[(size_t)(n0 + ty + j * 8) * CI_ + i0 + tx];
    __syncthreads();
#pragma unroll
    for (int j = 0; j < 4; ++j)
        O[(size_t)(i0 + ty + j * 8) * N_ + n0 + tx] = tl[tx][ty + j * 8];
}

__global__ __launch_bounds__(256) void k_castw(
    const float* __restrict__ wgr, const float* __restrict__ wgf,
    const float* __restrict__ wwr, const float* __restrict__ wwf,
    short* __restrict__ wgbf, short* __restrict__ wwbf)
{
    int which = blockIdx.y;
    size_t e = ((size_t)blockIdx.x * 256 + threadIdx.x) * 4;
    const float* src = which == 0 ? wgr : which == 1 ? wgf : which == 2 ? wwr : wwf;
    short* dst = which < 2 ? wgbf + (size_t)which * CI_ * C_
                           : wwbf + (size_t)(which - 2) * C_ * CI_;
    float4 v = *(const float4*)(src + e);
    short4 o; o.x = f2bf(v.x); o.y = f2bf(v.y); o.z = f2bf(v.z); o.w = f2bf(v.w);
    *(short4*)(dst + e) = o;
}

__global__ __launch_bounds__(256) void k_zero(float* __restrict__ a,
                                              float* __restrict__ b)
{
    int t = threadIdx.x;
    for (int i = t; i < 1024; i += 256) { a[i] = 0.f; b[i] = 0.f; }
}

__global__ __launch_bounds__(256) void k_bnfin(
    const float* __restrict__ bnsum, const float* __restrict__ bnssq,
    const float* __restrict__ gr, const float* __restrict__ br,
    const float* __restrict__ gf, const float* __restrict__ bfl,
    float* __restrict__ scale, float* __restrict__ shift)
{
    int t = blockIdx.x * 256 + threadIdx.x;      // 0..1023
    int st = t >> 9, c = t & 511;
    const float inv = 1.f / (float)(B_ * N_);
    float mean = bnsum[t] * inv;
    float var = bnssq[t] * inv - mean * mean;
    float g = st ? gf[c] : gr[c];
    float be = st ? bfl[c] : br[c];
    float sc = g * rsqrtf(var + EPS_);
    scale[t] = sc;
    shift[t] = be - mean * sc;
}

__global__ __launch_bounds__(256) void k_bnapply(
    const short* __restrict__ zbuf, const float* __restrict__ rgb,
    const float* __restrict__ flow, const float* __restrict__ scale,
    const float* __restrict__ shift, float* __restrict__ out)
{
    const size_t e = ((size_t)blockIdx.x * 256 + threadIdx.x) * 4;
    const size_t half = (size_t)B_ * C_ * N_;
    const int st = e >= half;
    const size_t rem = e - (size_t)st * half;
    const int c = (int)((rem >> 10) & (C_ - 1));
    const float* x = (st ? flow : rgb) + rem;
    const float sc = scale[st * C_ + c], sh = shift[st * C_ + c];
    short4 zb = *(const short4*)(zbuf + e);
    float4 xv = *(const float4*)x;
    float4 rr;
    rr.x = bf2f(zb.x) * sc + sh + xv.x;
    rr.y = bf2f(zb.y) * sc + sh + xv.y;
    rr.z = bf2f(zb.z) * sc + sh + xv.z;
    rr.w = bf2f(zb.w) * sc + sh + xv.w;
    *(float4*)(out + e) = rr;
}

// ---------------------------------------------------------------------------
extern "C" void kernel_launch(void* const* d_in, const int* in_sizes, int n_in,
                              void* d_out, int out_size, void* d_ws, size_t ws_size,
                              hipStream_t stream)
{
    const float* rgb        = (const float*)d_in[0];
    const float* flow       = (const float*)d_in[1];
    const float* wg_rgb     = (const float*)d_in[2];
    const float* bg_rgb     = (const float*)d_in[3];
    const float* wg_flow    = (const float*)d_in[4];
    const float* bg_flow    = (const float*)d_in[5];
    const float* ww_rgb     = (const float*)d_in[6];
    const float* bw_rgb     = (const float*)d_in[7];
    const float* gamma_rgb  = (const float*)d_in[8];
    const float* beta_rgb   = (const float*)d_in[9];
    const float* ww_flow    = (const float*)d_in[10];
    const float* bw_flow    = (const float*)d_in[11];
    const float* gamma_flow = (const float*)d_in[12];
    const float* beta_flow  = (const float*)d_in[13];
    float* out = (float*)d_out;

    char* p = (char*)d_ws;
    auto alloc = [&](size_t bytes) {
        void* q = (void*)p; p += (bytes + 255) & ~(size_t)255; return q;
    };
    short* wgbf  = (short*)alloc((size_t)2 * CI_ * C_ * 2);
    short* wwbf  = (short*)alloc((size_t)2 * C_ * CI_ * 2);
    float* scale = (float*)alloc(1024 * 4);
    float* shift = (float*)alloc(1024 * 4);
    float* bnsum = (float*)alloc(1024 * 4);
    float* bnssq = (float*)alloc(1024 * 4);
    short* zbuf  = (short*)alloc((size_t)2 * B_ * C_ * N_ * 2);

    const size_t fixed = (size_t)(p - (char*)d_ws);
    const size_t perb = (size_t)N_ * C_ * 4          // Xt (2 streams bf16)
                      + (size_t)N_ * CI_ * 4 * 3     // ref_t, ref_n, ybuf
                      + (size_t)N_ * N_ * 4          // S
                      + (size_t)8 * N_ * 16          // 4 partial arrays
                      + (size_t)N_ * 16 + 8192;      // finals + slop
    int nb = (int)((ws_size - fixed) / perb);
    if (nb > B_) nb = B_;
    if (nb < 1) nb = 1;

    short* Xt    = (short*)alloc((size_t)nb * N_ * C_ * 4);
    short* ref_t = (short*)alloc((size_t)nb * N_ * CI_ * 4);
    short* ref_n = (short*)alloc((size_t)nb * N_ * CI_ * 4);
    short* ybuf  = (short*)alloc((size_t)nb * N_ * CI_ * 4);
    float* S     = (float*)alloc((size_t)nb * N_ * N_ * 4);
    float* pRmax = (float*)alloc((size_t)nb * 8 * N_ * 4);
    float* pRsum = (float*)alloc((size_t)nb * 8 * N_ * 4);
    float* pCmax = (float*)alloc((size_t)nb * 8 * N_ * 4);
    float* pCsum = (float*)alloc((size_t)nb * 8 * N_ * 4);
    float* rmax  = (float*)alloc((size_t)nb * N_ * 4);
    float* rinv  = (float*)alloc((size_t)nb * N_ * 4);
    float* cmaxv = (float*)alloc((size_t)nb * N_ * 4);
    float* cinvv = (float*)alloc((size_t)nb * N_ * 4);

    k_zero<<<dim3(1), dim3(256), 0, stream>>>(bnsum, bnssq);
    k_castw<<<dim3(128, 4), dim3(256), 0, stream>>>(
        wg_rgb, wg_flow, ww_rgb, ww_flow, wgbf, wwbf);

    for (int b0 = 0; b0 < B_; b0 += nb) {
        int bc = (B_ - b0 < nb) ? (B_ - b0) : nb;
        k_tin<<<dim3(32, 16, bc * 2), dim3(256), 0, stream>>>(rgb, flow, Xt, b0);
        k_embed<<<dim3(2, 8, bc * 2), dim3(256), 0, stream>>>(
            Xt, wgbf, ref_t, bg_rgb, bg_flow);
        k_tbf<<<dim3(32, 8, bc * 2), dim3(256), 0, stream>>>(ref_t, ref_n);
        k_scores<<<dim3(8, 8, bc), dim3(256), 0, stream>>>(
            ref_t, S, pRmax, pRsum, pCmax, pCsum);
        k_sfin<<<dim3(8, bc), dim3(256), 0, stream>>>(
            pRmax, pRsum, pCmax, pCsum, rmax, rinv, cmaxv, cinvv);
        k_pv_rgb<<<dim3(2, 8, bc), dim3(256), 0, stream>>>(
            S, ref_n, rmax, rinv, ybuf);
        k_pv_flow<<<dim3(2, 8, bc), dim3(256), 0, stream>>>(
            S, ref_n, cmaxv, cinvv, ybuf);
        k_conv2bn<<<dim3(8, 4, bc * 2), dim3(256), 0, stream>>>(
            ybuf, wwbf, zbuf, bw_rgb, bw_flow, bnsum, bnssq, b0);
    }
    k_bnfin<<<dim3(4), dim3(256), 0, stream>>>(
        bnsum, bnssq, gamma_rgb, beta_rgb, gamma_flow, beta_flow, scale, shift);
    k_bnapply<<<dim3((2 * B_ * C_ * N_ / 4) / 256), dim3(256), 0, stream>>>(
        zbuf, rgb, flow, scale, shift, out);
}

// Round 6
// 309.817 us; speedup vs baseline: 2.8917x; 1.0931x over previous
//
#include <hip/hip_runtime.h>

#define B_   16
#define C_   512
#define CI_  256
#define N_   1024        // H*W
#define EPS_ 1e-5f

typedef _Float16 half_t;
typedef _Float16 f16x8 __attribute__((ext_vector_type(8)));
typedef _Float16 f16x4 __attribute__((ext_vector_type(4)));
typedef float    f32x4 __attribute__((ext_vector_type(4)));

#define ZERO_ACC(acc) \
    _Pragma("unroll") for (int mi = 0; mi < 4; ++mi) \
    _Pragma("unroll") for (int nj = 0; nj < 4; ++nj) { \
        acc[mi][nj][0]=0.f; acc[mi][nj][1]=0.f; acc[mi][nj][2]=0.f; acc[mi][nj][3]=0.f; }

// MFMA inner: 128x128 tile, 4 waves (2x2 of 64x64), 16x16x32 f16 frags.
__device__ __forceinline__ void mfma_tile16(
    const f16x8* As, const f16x8* Bs, int wr, int wc, int lr, int lk,
    f32x4 acc[4][4])
{
#pragma unroll
    for (int ks = 0; ks < 2; ++ks) {
        f16x8 af[4], bfr[4];
#pragma unroll
        for (int mi = 0; mi < 4; ++mi) {
            int r = wr + mi * 16 + lr;
            af[mi] = As[r * 8 + ((ks * 4 + lk) ^ (r & 7))];
        }
#pragma unroll
        for (int nj = 0; nj < 4; ++nj) {
            int c = wc + nj * 16 + lr;
            bfr[nj] = Bs[c * 8 + ((ks * 4 + lk) ^ (c & 7))];
        }
#pragma unroll
        for (int mi = 0; mi < 4; ++mi)
#pragma unroll
            for (int nj = 0; nj < 4; ++nj)
                acc[mi][nj] = __builtin_amdgcn_mfma_f32_16x16x32_f16(
                    af[mi], bfr[nj], acc[mi][nj], 0, 0, 0);
    }
}

// Stage both NT operands: rows are output dims, k contiguous.
__device__ __forceinline__ void stage_nt(
    const half_t* __restrict__ A, const half_t* __restrict__ Bp,
    int ldA, int ldB, int rowB, int colB, int k0,
    f16x8* As, f16x8* Bs, int t)
{
#pragma unroll
    for (int it = 0; it < 4; ++it) {
        int idx = it * 256 + t;
        int r = idx >> 3, c = idx & 7;
        As[r * 8 + (c ^ (r & 7))] =
            *(const f16x8*)(A + (size_t)(rowB + r) * ldA + k0 + c * 8);
        Bs[r * 8 + (c ^ (r & 7))] =
            *(const f16x8*)(Bp + (size_t)(colB + r) * ldB + k0 + c * 8);
    }
}

// Swizzled LDS index for the 128x136-half restage tile (16B-chunk XOR).
__device__ __forceinline__ int swz(int row, int col) {
    return row * 136 + ((((col >> 3) ^ (row & 7)) << 3) | (col & 7));
}

// Coalesced store of the restaged 128x128 tile. G pre-offset to tile origin.
__device__ __forceinline__ void tile_store(
    const half_t* sO, half_t* __restrict__ G, size_t ldO, int t)
{
#pragma unroll
    for (int it = 0; it < 8; ++it) {
        int rr = it * 16 + (t >> 4);
        int ch = t & 15;
        f16x8 v = *(const f16x8*)(sO + rr * 136 + ((ch ^ (rr & 7)) << 3));
        *(f16x8*)(G + (size_t)rr * ldO + ch * 8) = v;
    }
}

// ---------------------------------------------------------------------------
// K1: embed GEMM. out[n][i] = sum_c Xt[n][c]*wg[i][c] + bg[i].
// Writes ref_t [n][i] AND ref_n [i][n] (dual restage, kills tbf kernel).
__global__ __launch_bounds__(256) void k_embed(
    const half_t* __restrict__ Xt, const half_t* __restrict__ wgbf,
    half_t* __restrict__ ref_t, half_t* __restrict__ ref_n,
    const float* __restrict__ bg_rgb, const float* __restrict__ bg_flow)
{
    __shared__ __align__(16) char SMEM[34816];
    f16x8* As = (f16x8*)SMEM;
    f16x8* Bs = As + 1024;
    half_t* sO = (half_t*)SMEM;
    const int z = blockIdx.z, st = z & 1;
    const half_t* A = Xt + (size_t)z * N_ * C_;
    const half_t* Bp = wgbf + (size_t)st * CI_ * C_;
    const float* bias = st ? bg_flow : bg_rgb;
    const int rowB = blockIdx.y * 128, colB = blockIdx.x * 128;
    const int t = threadIdx.x, w = t >> 6, l = t & 63;
    const int wr = (w >> 1) * 64, wc = (w & 1) * 64, lr = l & 15, lk = l >> 4;
    f32x4 acc[4][4]; ZERO_ACC(acc);

    for (int k0 = 0; k0 < C_; k0 += 64) {
        stage_nt(A, Bp, C_, C_, rowB, colB, k0, As, Bs, t);
        __syncthreads();
        mfma_tile16(As, Bs, wr, wc, lr, lk, acc);
        __syncthreads();
    }
    half_t hv[4][4][4];
#pragma unroll
    for (int mi = 0; mi < 4; ++mi)
#pragma unroll
        for (int q = 0; q < 4; ++q)
#pragma unroll
            for (int nj = 0; nj < 4; ++nj) {
                int cg = wc + nj * 16 + lr;
                hv[mi][q][nj] = (half_t)(acc[mi][nj][q] + bias[colB + cg]);
            }
    // pass 1: [n][i] -> ref_t
#pragma unroll
    for (int mi = 0; mi < 4; ++mi)
#pragma unroll
        for (int q = 0; q < 4; ++q)
#pragma unroll
            for (int nj = 0; nj < 4; ++nj)
                sO[swz(wr + mi * 16 + lk * 4 + q, wc + nj * 16 + lr)] =
                    hv[mi][q][nj];
    __syncthreads();
    tile_store(sO, ref_t + (size_t)z * N_ * CI_ + (size_t)rowB * CI_ + colB,
               CI_, t);
    __syncthreads();
    // pass 2: [i][n] -> ref_n
#pragma unroll
    for (int mi = 0; mi < 4; ++mi)
#pragma unroll
        for (int q = 0; q < 4; ++q)
#pragma unroll
            for (int nj = 0; nj < 4; ++nj)
                sO[swz(wc + nj * 16 + lr, wr + mi * 16 + lk * 4 + q)] =
                    hv[mi][q][nj];
    __syncthreads();
    tile_store(sO, ref_n + (size_t)z * CI_ * N_ + (size_t)colB * N_ + rowB,
               N_, t);
}

// ---------------------------------------------------------------------------
// K2: scores GEMM + row/col partial stats + P16 = fp16(exp(S - rowmax_blk)).
__global__ __launch_bounds__(256) void k_scores(
    const half_t* __restrict__ ref_t, half_t* __restrict__ P16,
    float* __restrict__ pRmax, float* __restrict__ pRsum,
    float* __restrict__ pCmax, float* __restrict__ pCsum)
{
    __shared__ __align__(16) char SMEM[34816];
    f16x8* As = (f16x8*)SMEM;
    f16x8* Bs = As + 1024;
    half_t* sO = (half_t*)SMEM;
    float (*redM)[2]  = (float(*)[2])(SMEM + 32768);
    float (*redS2)[2] = (float(*)[2])(SMEM + 32768 + 1024);
    const int z = blockIdx.z;
    const half_t* A  = ref_t + (size_t)(2 * z) * N_ * CI_;
    const half_t* Bp = ref_t + (size_t)(2 * z + 1) * N_ * CI_;
    const int rowB = blockIdx.y * 128, colB = blockIdx.x * 128;
    const int t = threadIdx.x, w = t >> 6, l = t & 63;
    const int wr = (w >> 1) * 64, wc = (w & 1) * 64, lr = l & 15, lk = l >> 4;
    f32x4 acc[4][4]; ZERO_ACC(acc);

    for (int k0 = 0; k0 < CI_; k0 += 64) {
        stage_nt(A, Bp, CI_, CI_, rowB, colB, k0, As, Bs, t);
        __syncthreads();
        mfma_tile16(As, Bs, wr, wc, lr, lk, acc);
        __syncthreads();
    }
    // ---- row partial max over this block's 128 cols ----
    float Mrow[4][4];
#pragma unroll
    for (int mi = 0; mi < 4; ++mi)
#pragma unroll
        for (int q = 0; q < 4; ++q) {
            float mx = fmaxf(fmaxf(acc[mi][0][q], acc[mi][1][q]),
                             fmaxf(acc[mi][2][q], acc[mi][3][q]));
#pragma unroll
            for (int d = 1; d < 16; d <<= 1) mx = fmaxf(mx, __shfl_xor(mx, d));
            if (lr == 0) redM[wr + mi * 16 + lk * 4 + q][w & 1] = mx;
        }
    __syncthreads();
#pragma unroll
    for (int mi = 0; mi < 4; ++mi)
#pragma unroll
        for (int q = 0; q < 4; ++q) {
            int rl = wr + mi * 16 + lk * 4 + q;
            Mrow[mi][q] = fmaxf(redM[rl][0], redM[rl][1]);
        }
    // ---- P16 values (reused for row sums) ----
    half_t pk[4][4][4];
#pragma unroll
    for (int mi = 0; mi < 4; ++mi)
#pragma unroll
        for (int q = 0; q < 4; ++q) {
            float s = 0.f;
#pragma unroll
            for (int nj = 0; nj < 4; ++nj) {
                float pv = __expf(acc[mi][nj][q] - Mrow[mi][q]);
                pk[mi][q][nj] = (half_t)pv;
                s += pv;
            }
#pragma unroll
            for (int d = 1; d < 16; d <<= 1) s += __shfl_xor(s, d);
            if (lr == 0) redS2[wr + mi * 16 + lk * 4 + q][w & 1] = s;
        }
    __syncthreads();
    if (t < 128) {
        float M = fmaxf(redM[t][0], redM[t][1]);
        float sm = redS2[t][0] + redS2[t][1];
        size_t o = (((size_t)z * 8 + blockIdx.x) << 10) + rowB + t;
        pRmax[o] = M; pRsum[o] = sm;
    }
    __syncthreads();
    // ---- col partials over this block's 128 rows ----
#pragma unroll
    for (int nj = 0; nj < 4; ++nj) {
        float mx = -1e30f;
#pragma unroll
        for (int mi = 0; mi < 4; ++mi)
#pragma unroll
            for (int q = 0; q < 4; ++q) mx = fmaxf(mx, acc[mi][nj][q]);
        mx = fmaxf(mx, __shfl_xor(mx, 16));
        mx = fmaxf(mx, __shfl_xor(mx, 32));
        if (lk == 0) redM[wc + nj * 16 + lr][w >> 1] = mx;
    }
    __syncthreads();
    float Mcol[4];
#pragma unroll
    for (int nj = 0; nj < 4; ++nj) {
        int cl = wc + nj * 16 + lr;
        Mcol[nj] = fmaxf(redM[cl][0], redM[cl][1]);
    }
#pragma unroll
    for (int nj = 0; nj < 4; ++nj) {
        float s = 0.f;
#pragma unroll
        for (int mi = 0; mi < 4; ++mi)
#pragma unroll
            for (int q = 0; q < 4; ++q)
                s += __expf(acc[mi][nj][q] - Mcol[nj]);
        s += __shfl_xor(s, 16);
        s += __shfl_xor(s, 32);
        if (lk == 0) redS2[wc + nj * 16 + lr][w >> 1] = s;
    }
    __syncthreads();
    if (t < 128) {
        float M = fmaxf(redM[t][0], redM[t][1]);
        float sm = redS2[t][0] + redS2[t][1];
        size_t o = (((size_t)z * 8 + blockIdx.y) << 10) + colB + t;
        pCmax[o] = M; pCsum[o] = sm;
    }
    __syncthreads();
    // ---- restage P16 + coalesced store ----
#pragma unroll
    for (int mi = 0; mi < 4; ++mi)
#pragma unroll
        for (int q = 0; q < 4; ++q)
#pragma unroll
            for (int nj = 0; nj < 4; ++nj)
                sO[swz(wr + mi * 16 + lk * 4 + q, wc + nj * 16 + lr)] =
                    pk[mi][q][nj];
    __syncthreads();
    tile_store(sO, P16 + (size_t)z * N_ * N_ + (size_t)rowB * N_ + colB, N_, t);
}

// K3: combine 8 partials -> rmax/rinv, cmax/cinv.
__global__ __launch_bounds__(256) void k_sfin(
    const float* __restrict__ pRmax, const float* __restrict__ pRsum,
    const float* __restrict__ pCmax, const float* __restrict__ pCsum,
    float* __restrict__ rmax, float* __restrict__ rinv,
    float* __restrict__ cmax, float* __restrict__ cinv)
{
    const int z = blockIdx.y;
    const int part = blockIdx.x;
    const int isCol = part >> 2;
    const int n = (part & 3) * 256 + threadIdx.x;
    const float* pM = (isCol ? pCmax : pRmax) + (((size_t)z * 8) << 10) + n;
    const float* pS = (isCol ? pCsum : pRsum) + (((size_t)z * 8) << 10) + n;
    float M = -1e30f;
#pragma unroll
    for (int j = 0; j < 8; ++j) M = fmaxf(M, pM[(size_t)j << 10]);
    float s = 0.f;
#pragma unroll
    for (int j = 0; j < 8; ++j)
        s += pS[(size_t)j << 10] * __expf(pM[(size_t)j << 10] - M);
    float* oM = isCol ? cmax : rmax;
    float* oI = isCol ? cinv : rinv;
    oM[(size_t)z * N_ + n] = M;
    oI[(size_t)z * N_ + n] = 1.f / s;
}

// ---------------------------------------------------------------------------
// K4: rgb PV. O[n][i] = sum_m (P16[n][m]*f[n,kblk]) * fe[i][m]; f precomputed.
__global__ __launch_bounds__(256) void k_pv_rgb(
    const half_t* __restrict__ P16, const half_t* __restrict__ ref_n,
    const float* __restrict__ pRmax, const float* __restrict__ rmax,
    const float* __restrict__ rinv, half_t* __restrict__ ybuf)
{
    __shared__ __align__(16) char SMEM[36864];
    f16x8* As = (f16x8*)SMEM;
    f16x8* Bs = As + 1024;
    half_t* sO = (half_t*)SMEM;
    float* fact = (float*)(SMEM + 32768);     // [8 kblk][128 rows]
    const int z = blockIdx.z;
    const half_t* Pz = P16 + (size_t)z * N_ * N_;
    const half_t* Bp = ref_n + (size_t)(2 * z + 1) * CI_ * N_;   // fe [i][m]
    const int rowB = blockIdx.y * 128, colB = blockIdx.x * 128;
    const int t = threadIdx.x, w = t >> 6, l = t & 63;
    const int wr = (w >> 1) * 64, wc = (w & 1) * 64, lr = l & 15, lk = l >> 4;
#pragma unroll
    for (int i = 0; i < 4; ++i) {
        int idx = i * 256 + t;                // kblk*128 + r
        int kb = idx >> 7, r = idx & 127;
        int n = rowB + r;
        fact[idx] = __expf(pRmax[(((size_t)z * 8 + kb) << 10) + n]
                           - rmax[(size_t)z * N_ + n]) * rinv[(size_t)z * N_ + n];
    }
    __syncthreads();
    f32x4 acc[4][4]; ZERO_ACC(acc);

    for (int k0 = 0; k0 < N_; k0 += 64) {
        const int kb = k0 >> 7;
#pragma unroll
        for (int it = 0; it < 4; ++it) {
            int idx = it * 256 + t;
            int r = idx >> 3, c8 = idx & 7;
            f16x8 pv = *(const f16x8*)(Pz + (size_t)(rowB + r) * N_ + k0 + c8 * 8);
            half_t fh = (half_t)fact[(kb << 7) + r];
            f16x8 pkv;
#pragma unroll
            for (int j = 0; j < 8; ++j) pkv[j] = pv[j] * fh;
            As[r * 8 + (c8 ^ (r & 7))] = pkv;
            Bs[r * 8 + (c8 ^ (r & 7))] =
                *(const f16x8*)(Bp + (size_t)(colB + r) * N_ + k0 + c8 * 8);
        }
        __syncthreads();
        mfma_tile16(As, Bs, wr, wc, lr, lk, acc);
        __syncthreads();
    }
#pragma unroll
    for (int mi = 0; mi < 4; ++mi)
#pragma unroll
        for (int q = 0; q < 4; ++q)
#pragma unroll
            for (int nj = 0; nj < 4; ++nj)
                sO[swz(wr + mi * 16 + lk * 4 + q, wc + nj * 16 + lr)] =
                    (half_t)acc[mi][nj][q];
    __syncthreads();
    tile_store(sO, ybuf + (size_t)(2 * z) * N_ * CI_ + (size_t)rowB * CI_ + colB,
               CI_, t);
}

// K5: flow PV. O[m][i] = sum_n (P16[n][m]*en[n]*em[m]) * re[i][n].
__global__ __launch_bounds__(256) void k_pv_flow(
    const half_t* __restrict__ P16, const half_t* __restrict__ ref_n,
    const float* __restrict__ pRmax, const float* __restrict__ cmax,
    const float* __restrict__ cinv, half_t* __restrict__ ybuf)
{
    __shared__ __align__(16) char SMEM[54784];
    f16x8* As = (f16x8*)SMEM;
    f16x8* Bs = As + 1024;
    half_t* sO = (half_t*)SMEM;
    half_t* Ss = (half_t*)(SMEM + 32768);     // [64][136]
    float* en = (float*)(SMEM + 50176);       // [1024]
    float* em = (float*)(SMEM + 54272);       // [128]
    const int z = blockIdx.z;
    const half_t* Pz = P16 + (size_t)z * N_ * N_;
    const half_t* Bp = ref_n + (size_t)(2 * z) * CI_ * N_;       // re [i][n]
    const int rowB = blockIdx.y * 128;        // m
    const int colB = blockIdx.x * 128;        // i
    const int mblk = rowB >> 7;
    const int t = threadIdx.x, w = t >> 6, l = t & 63;
    const int wr = (w >> 1) * 64, wc = (w & 1) * 64, lr = l & 15, lk = l >> 4;
#pragma unroll
    for (int i = 0; i < 4; ++i) {
        int n = i * 256 + t;
        en[n] = __expf(pRmax[(((size_t)z * 8 + mblk) << 10) + n]);
    }
    if (t < 128)
        em[t] = __expf(-cmax[(size_t)z * N_ + rowB + t]) *
                cinv[(size_t)z * N_ + rowB + t];
    __syncthreads();
    f32x4 acc[4][4]; ZERO_ACC(acc);

    for (int k0 = 0; k0 < N_; k0 += 64) {
        // stage1: P16 rows (coalesced) -> Ss; B direct
#pragma unroll
        for (int it = 0; it < 4; ++it) {
            int idx = it * 256 + t;
            int rr = idx >> 4, c8 = idx & 15;
            *(f16x8*)(Ss + rr * 136 + c8 * 8) =
                *(const f16x8*)(Pz + (size_t)(k0 + rr) * N_ + rowB + c8 * 8);
        }
#pragma unroll
        for (int it = 0; it < 4; ++it) {
            int idx = it * 256 + t;
            int r = idx >> 3, c = idx & 7;
            Bs[r * 8 + (c ^ (r & 7))] =
                *(const f16x8*)(Bp + (size_t)(colB + r) * N_ + k0 + c * 8);
        }
        __syncthreads();
        // stage2: transpose + rank-1 rescale -> As
#pragma unroll
        for (int i = 0; i < 4; ++i) {
            int idx = i * 256 + t;
            int m = idx & 127, oct = idx >> 7;
            float e_m = em[m];
            f16x8 pkv;
#pragma unroll
            for (int j = 0; j < 8; ++j) {
                float v = (float)Ss[(oct * 8 + j) * 136 + m]
                          * en[k0 + oct * 8 + j] * e_m;
                pkv[j] = (half_t)v;
            }
            As[m * 8 + (oct ^ (m & 7))] = pkv;
        }
        __syncthreads();
        mfma_tile16(As, Bs, wr, wc, lr, lk, acc);
        __syncthreads();
    }
#pragma unroll
    for (int mi = 0; mi < 4; ++mi)
#pragma unroll
        for (int q = 0; q < 4; ++q)
#pragma unroll
            for (int nj = 0; nj < 4; ++nj)
                sO[swz(wr + mi * 16 + lk * 4 + q, wc + nj * 16 + lr)] =
                    (half_t)acc[mi][nj][q];
    __syncthreads();
    tile_store(sO, ybuf + (size_t)(2 * z + 1) * N_ * CI_ +
                   (size_t)rowB * CI_ + colB, CI_, t);
}

// ---------------------------------------------------------------------------
// K6: conv2 GEMM -> fp16 z + fused BN partial stats.
__global__ __launch_bounds__(256) void k_conv2bn(
    const half_t* __restrict__ ybuf, const half_t* __restrict__ wwbf,
    half_t* __restrict__ zbuf, const float* __restrict__ bw_rgb,
    const float* __restrict__ bw_flow, float* __restrict__ bnsum,
    float* __restrict__ bnssq, int b0)
{
    __shared__ __align__(16) char SMEM[34816];
    f16x8* As = (f16x8*)SMEM;
    f16x8* Bs = As + 1024;
    half_t* sO = (half_t*)SMEM;
    float (*redS)[2] = (float(*)[2])(SMEM + 32768);
    float (*redQ)[2] = (float(*)[2])(SMEM + 32768 + 1024);
    const int z = blockIdx.z, lb = z >> 1, st = z & 1;
    const int gb = b0 + lb;
    const half_t* A = wwbf + (size_t)st * C_ * CI_;
    const half_t* Bp = ybuf + (size_t)z * N_ * CI_;
    const float* bias = st ? bw_flow : bw_rgb;
    half_t* O = zbuf + ((size_t)st * B_ + gb) * C_ * N_;
    const int rowB = blockIdx.y * 128;   // c
    const int colB = blockIdx.x * 128;   // n
    const int t = threadIdx.x, w = t >> 6, l = t & 63;
    const int wr = (w >> 1) * 64, wc = (w & 1) * 64, lr = l & 15, lk = l >> 4;
    f32x4 acc[4][4]; ZERO_ACC(acc);

    for (int k0 = 0; k0 < CI_; k0 += 64) {
        stage_nt(A, Bp, CI_, CI_, rowB, colB, k0, As, Bs, t);
        __syncthreads();
        mfma_tile16(As, Bs, wr, wc, lr, lk, acc);
        __syncthreads();
    }
    half_t hv[4][4][4];
#pragma unroll
    for (int mi = 0; mi < 4; ++mi)
#pragma unroll
        for (int q = 0; q < 4; ++q) {
            int rg = rowB + wr + mi * 16 + lk * 4 + q;
            float bv = bias[rg];
            float s = 0.f, ss = 0.f;
#pragma unroll
            for (int nj = 0; nj < 4; ++nj) {
                half_t h = (half_t)(acc[mi][nj][q] + bv);
                hv[mi][q][nj] = h;
                float v = (float)h;
                s += v; ss += v * v;
            }
#pragma unroll
            for (int d = 1; d < 16; d <<= 1) {
                s += __shfl_xor(s, d);
                ss += __shfl_xor(ss, d);
            }
            if (lr == 0) {
                redS[wr + mi * 16 + lk * 4 + q][w & 1] = s;
                redQ[wr + mi * 16 + lk * 4 + q][w & 1] = ss;
            }
        }
    __syncthreads();
    if (t < 128) {
        atomicAdd(&bnsum[st * C_ + rowB + t], redS[t][0] + redS[t][1]);
        atomicAdd(&bnssq[st * C_ + rowB + t], redQ[t][0] + redQ[t][1]);
    }
    __syncthreads();
#pragma unroll
    for (int mi = 0; mi < 4; ++mi)
#pragma unroll
        for (int q = 0; q < 4; ++q)
#pragma unroll
            for (int nj = 0; nj < 4; ++nj)
                sO[swz(wr + mi * 16 + lk * 4 + q, wc + nj * 16 + lr)] =
                    hv[mi][q][nj];
    __syncthreads();
    tile_store(sO, O + (size_t)rowB * N_ + colB, N_, t);
}

// Memory passes --------------------------------------------------------------
__global__ __launch_bounds__(256) void k_tin(
    const float* __restrict__ rgb, const float* __restrict__ flow,
    half_t* __restrict__ Xt, int b0)
{
    int z = blockIdx.z, lb = z >> 1, st = z & 1;
    const float* X = (st ? flow : rgb) + (size_t)(b0 + lb) * C_ * N_;
    half_t* O = Xt + (size_t)z * N_ * C_;
    __shared__ float tl[32][33];
    int n0 = blockIdx.x * 32, c0 = blockIdx.y * 32;
    int tx = threadIdx.x & 31, ty = threadIdx.x >> 5;
#pragma unroll
    for (int j = 0; j < 4; ++j)
        tl[ty + j * 8][tx] = X[(size_t)(c0 + ty + j * 8) * N_ + n0 + tx];
    __syncthreads();
#pragma unroll
    for (int j = 0; j < 4; ++j)
        O[(size_t)(n0 + ty + j * 8) * C_ + c0 + tx] =
            (half_t)tl[tx][ty + j * 8];
}

__global__ __launch_bounds__(256) void k_castw(
    const float* __restrict__ wgr, const float* __restrict__ wgf,
    const float* __restrict__ wwr, const float* __restrict__ wwf,
    half_t* __restrict__ wgbf, half_t* __restrict__ wwbf)
{
    int which = blockIdx.y;
    size_t e = ((size_t)blockIdx.x * 256 + threadIdx.x) * 4;
    const float* src = which == 0 ? wgr : which == 1 ? wgf : which == 2 ? wwr : wwf;
    half_t* dst = which < 2 ? wgbf + (size_t)which * CI_ * C_
                            : wwbf + (size_t)(which - 2) * C_ * CI_;
    float4 v = *(const float4*)(src + e);
    f16x4 o; o[0] = (half_t)v.x; o[1] = (half_t)v.y;
    o[2] = (half_t)v.z; o[3] = (half_t)v.w;
    *(f16x4*)(dst + e) = o;
}

__global__ __launch_bounds__(256) void k_zero(float* __restrict__ a,
                                              float* __restrict__ b)
{
    int t = threadIdx.x;
    for (int i = t; i < 1024; i += 256) { a[i] = 0.f; b[i] = 0.f; }
}

__global__ __launch_bounds__(256) void k_bnfin(
    const float* __restrict__ bnsum, const float* __restrict__ bnssq,
    const float* __restrict__ gr, const float* __restrict__ br,
    const float* __restrict__ gf, const float* __restrict__ bfl,
    float* __restrict__ scale, float* __restrict__ shift)
{
    int t = blockIdx.x * 256 + threadIdx.x;
    int st = t >> 9, c = t & 511;
    const float inv = 1.f / (float)(B_ * N_);
    float mean = bnsum[t] * inv;
    float var = bnssq[t] * inv - mean * mean;
    float g = st ? gf[c] : gr[c];
    float be = st ? bfl[c] : br[c];
    float sc = g * rsqrtf(var + EPS_);
    scale[t] = sc;
    shift[t] = be - mean * sc;
}

__global__ __launch_bounds__(256) void k_bnapply(
    const half_t* __restrict__ zbuf, const float* __restrict__ rgb,
    const float* __restrict__ flow, const float* __restrict__ scale,
    const float* __restrict__ shift, float* __restrict__ out)
{
    const size_t e = ((size_t)blockIdx.x * 256 + threadIdx.x) * 4;
    const size_t half_sz = (size_t)B_ * C_ * N_;
    const int st = e >= half_sz;
    const size_t rem = e - (size_t)st * half_sz;
    const int c = (int)((rem >> 10) & (C_ - 1));
    const float* x = (st ? flow : rgb) + rem;
    const float sc = scale[st * C_ + c], sh = shift[st * C_ + c];
    f16x4 zb = *(const f16x4*)(zbuf + e);
    float4 xv = *(const float4*)x;
    float4 rr;
    rr.x = (float)zb[0] * sc + sh + xv.x;
    rr.y = (float)zb[1] * sc + sh + xv.y;
    rr.z = (float)zb[2] * sc + sh + xv.z;
    rr.w = (float)zb[3] * sc + sh + xv.w;
    *(float4*)(out + e) = rr;
}

// ---------------------------------------------------------------------------
extern "C" void kernel_launch(void* const* d_in, const int* in_sizes, int n_in,
                              void* d_out, int out_size, void* d_ws, size_t ws_size,
                              hipStream_t stream)
{
    const float* rgb        = (const float*)d_in[0];
    const float* flow       = (const float*)d_in[1];
    const float* wg_rgb     = (const float*)d_in[2];
    const float* bg_rgb     = (const float*)d_in[3];
    const float* wg_flow    = (const float*)d_in[4];
    const float* bg_flow    = (const float*)d_in[5];
    const float* ww_rgb     = (const float*)d_in[6];
    const float* bw_rgb     = (const float*)d_in[7];
    const float* gamma_rgb  = (const float*)d_in[8];
    const float* beta_rgb   = (const float*)d_in[9];
    const float* ww_flow    = (const float*)d_in[10];
    const float* bw_flow    = (const float*)d_in[11];
    const float* gamma_flow = (const float*)d_in[12];
    const float* beta_flow  = (const float*)d_in[13];
    float* out = (float*)d_out;

    char* p = (char*)d_ws;
    auto alloc = [&](size_t bytes) {
        void* q = (void*)p; p += (bytes + 255) & ~(size_t)255; return q;
    };
    half_t* wgbf  = (half_t*)alloc((size_t)2 * CI_ * C_ * 2);
    half_t* wwbf  = (half_t*)alloc((size_t)2 * C_ * CI_ * 2);
    float* scale = (float*)alloc(1024 * 4);
    float* shift = (float*)alloc(1024 * 4);
    float* bnsum = (float*)alloc(1024 * 4);
    float* bnssq = (float*)alloc(1024 * 4);
    half_t* zbuf  = (half_t*)alloc((size_t)2 * B_ * C_ * N_ * 2);

    const size_t fixed = (size_t)(p - (char*)d_ws);
    const size_t perb = (size_t)N_ * C_ * 2 * 2       // Xt
                      + (size_t)N_ * CI_ * 2 * 2 * 3  // ref_t, ref_n, ybuf
                      + (size_t)N_ * N_ * 2           // P16
                      + (size_t)8 * N_ * 16           // partials
                      + (size_t)N_ * 16 + 16384;      // finals + slop
    int nb = (int)((ws_size - fixed) / perb);
    if (nb > B_) nb = B_;
    if (nb < 1) nb = 1;

    half_t* Xt    = (half_t*)alloc((size_t)nb * N_ * C_ * 2 * 2);
    half_t* ref_t = (half_t*)alloc((size_t)nb * N_ * CI_ * 2 * 2);
    half_t* ref_n = (half_t*)alloc((size_t)nb * N_ * CI_ * 2 * 2);
    half_t* ybuf  = (half_t*)alloc((size_t)nb * N_ * CI_ * 2 * 2);
    half_t* P16   = (half_t*)alloc((size_t)nb * N_ * N_ * 2);
    float* pRmax = (float*)alloc((size_t)nb * 8 * N_ * 4);
    float* pRsum = (float*)alloc((size_t)nb * 8 * N_ * 4);
    float* pCmax = (float*)alloc((size_t)nb * 8 * N_ * 4);
    float* pCsum = (float*)alloc((size_t)nb * 8 * N_ * 4);
    float* rmax  = (float*)alloc((size_t)nb * N_ * 4);
    float* rinv  = (float*)alloc((size_t)nb * N_ * 4);
    float* cmaxv = (float*)alloc((size_t)nb * N_ * 4);
    float* cinvv = (float*)alloc((size_t)nb * N_ * 4);

    k_zero<<<dim3(1), dim3(256), 0, stream>>>(bnsum, bnssq);
    k_castw<<<dim3(128, 4), dim3(256), 0, stream>>>(
        wg_rgb, wg_flow, ww_rgb, ww_flow, wgbf, wwbf);

    for (int b0 = 0; b0 < B_; b0 += nb) {
        int bc = (B_ - b0 < nb) ? (B_ - b0) : nb;
        k_tin<<<dim3(32, 16, bc * 2), dim3(256), 0, stream>>>(rgb, flow, Xt, b0);
        k_embed<<<dim3(2, 8, bc * 2), dim3(256), 0, stream>>>(
            Xt, wgbf, ref_t, ref_n, bg_rgb, bg_flow);
        k_scores<<<dim3(8, 8, bc), dim3(256), 0, stream>>>(
            ref_t, P16, pRmax, pRsum, pCmax, pCsum);
        k_sfin<<<dim3(8, bc), dim3(256), 0, stream>>>(
            pRmax, pRsum, pCmax, pCsum, rmax, rinv, cmaxv, cinvv);
        k_pv_rgb<<<dim3(2, 8, bc), dim3(256), 0, stream>>>(
            P16, ref_n, pRmax, rmax, rinv, ybuf);
        k_pv_flow<<<dim3(2, 8, bc), dim3(256), 0, stream>>>(
            P16, ref_n, pRmax, cmaxv, cinvv, ybuf);
        k_conv2bn<<<dim3(8, 4, bc * 2), dim3(256), 0, stream>>>(
            ybuf, wwbf, zbuf, bw_rgb, bw_flow, bnsum, bnssq, b0);
    }
    k_bnfin<<<dim3(4), dim3(256), 0, stream>>>(
        bnsum, bnssq, gamma_rgb, beta_rgb, gamma_flow, beta_flow, scale, shift);
    k_bnapply<<<dim3((2 * B_ * C_ * N_ / 4) / 256), dim3(256), 0, stream>>>(
        zbuf, rgb, flow, scale, shift, out);
}